// Round 5
// baseline (343.211 us; speedup 1.0000x reference)
//
#include <hip/hip_runtime.h>

#define N_HID 128
#define LEAKY 0.01f
#define SCAN_B 256

// ---------------------------------------------------------------------------
// helpers
// ---------------------------------------------------------------------------
__device__ inline ushort f2bf_rne(float f) {   // f32 -> bf16, round-nearest-even
    unsigned u = __float_as_uint(f);
    u += 0x7fffu + ((u >> 16) & 1u);
    return (ushort)(u >> 16);
}

__device__ inline int load_idx(const void* eidx, long long pos, int is64) {
    if (is64) return (int)((const long long*)eidx)[pos];
    return ((const int*)eidx)[pos];
}

// ---------------------------------------------------------------------------
// K0: detect int64 vs int32 edge_index.
// ---------------------------------------------------------------------------
__global__ void detect_dtype_k(const void* __restrict__ eidx, long long n_i64,
                               int* __restrict__ flag) {
    __shared__ int nonzero_hi;
    if (threadIdx.x == 0) nonzero_hi = 0;
    __syncthreads();
    const long long* p = (const long long*)eidx;
    long long samples = n_i64 < 4096 ? n_i64 : 4096;
    int bad = 0;
    for (long long k = threadIdx.x; k < samples; k += blockDim.x) {
        if ((p[k] >> 32) != 0) bad = 1;
    }
    if (bad) atomicOr(&nonzero_hi, 1);
    __syncthreads();
    if (threadIdx.x == 0) *flag = nonzero_hi ? 0 : 1;  // 1 => int64
}

// ---------------------------------------------------------------------------
// K1: per-node logits ei = x.w_i, ej = x.w_j (wave/node, shfl reduce).
// Fused: bf16-quantize the x row into xb, zero denom/deg.
// ---------------------------------------------------------------------------
__global__ __launch_bounds__(256) void node_logits_k(
        const float* __restrict__ x, const float* __restrict__ w_i,
        const float* __restrict__ w_j, float* __restrict__ ei_all,
        float* __restrict__ ej_all, float* __restrict__ denom,
        int* __restrict__ deg, ushort* __restrict__ xb, int n) {
    int wave = (int)((blockIdx.x * (long long)blockDim.x + threadIdx.x) >> 6);
    int lane = threadIdx.x & 63;
    if (wave >= n) return;
    const float2* xr = (const float2*)(x + (long long)wave * N_HID);
    float2 v  = xr[lane];
    float2 wi = ((const float2*)w_i)[lane];
    float2 wj = ((const float2*)w_j)[lane];
    if (xb) {
        unsigned packed = (unsigned)f2bf_rne(v.x) | ((unsigned)f2bf_rne(v.y) << 16);
        ((unsigned*)(xb + (long long)wave * N_HID))[lane] = packed;
    }
    float si = v.x * wi.x + v.y * wi.y;
    float sj = v.x * wj.x + v.y * wj.y;
    #pragma unroll
    for (int off = 32; off >= 1; off >>= 1) {
        si += __shfl_xor(si, off);
        sj += __shfl_xor(sj, off);
    }
    if (lane == 0) {
        ei_all[wave] = si;
        ej_all[wave] = sj;
        denom[wave]  = 0.f;
        deg[wave]    = 0;
    }
}

// ---------------------------------------------------------------------------
// K2: per-edge, 4 edges/thread (strided phases, static register arrays):
//   p = exp(leaky(ei[i]+ej[j])); denom[j] += p (native f32 atomic);
//   rank[k] = deg[i]++ (native int atomic).
// Segment-max skipped: |e| small, exp stays in f32 range, max cancels in ratio.
// ---------------------------------------------------------------------------
__global__ __launch_bounds__(256) void edge_exp_k(
        const void* __restrict__ eidx, const int* __restrict__ flag,
        const float* __restrict__ ei_all, const float* __restrict__ ej_all,
        float* __restrict__ denom, int* __restrict__ deg,
        ushort* __restrict__ rank, long long E, long long T) {
    long long t = blockIdx.x * (long long)blockDim.x + threadIdx.x;
    if (t >= T) return;                       // tail guard (round-4 bug fix)
    int is64 = *flag;

    bool vv[4];
    int jj[4], ii[4];
    float pp[4];
    #pragma unroll
    for (int m = 0; m < 4; ++m) {
        long long k = t + (long long)m * T;
        vv[m] = (k < E);
        jj[m] = vv[m] ? load_idx(eidx, k, is64) : 0;
        ii[m] = vv[m] ? load_idx(eidx, E + k, is64) : 0;
    }
    #pragma unroll
    for (int m = 0; m < 4; ++m) {
        float e = ei_all[ii[m]] + ej_all[jj[m]];   // index 0 if invalid: safe
        e = e > 0.f ? e : LEAKY * e;
        pp[m] = __expf(e);
    }
    #pragma unroll
    for (int m = 0; m < 4; ++m)
        if (vv[m]) unsafeAtomicAdd(&denom[jj[m]], pp[m]);
    int rr[4];
    #pragma unroll
    for (int m = 0; m < 4; ++m)
        rr[m] = vv[m] ? atomicAdd(&deg[ii[m]], 1) : 0;
    #pragma unroll
    for (int m = 0; m < 4; ++m)
        if (vv[m]) rank[t + (long long)m * T] = (ushort)rr[m];
}

// ---------------------------------------------------------------------------
// Scan (exclusive prefix sum of deg -> start), 3 tiny kernels, n = 100k.
// ---------------------------------------------------------------------------
__global__ __launch_bounds__(SCAN_B) void scan1_k(const int* __restrict__ deg,
                                                  int* __restrict__ start,
                                                  int* __restrict__ bsum, int n) {
    __shared__ int tmp[SCAN_B];
    int gid = blockIdx.x * SCAN_B + threadIdx.x;
    int v = (gid < n) ? deg[gid] : 0;
    tmp[threadIdx.x] = v;
    __syncthreads();
    for (int off = 1; off < SCAN_B; off <<= 1) {
        int t = (threadIdx.x >= off) ? tmp[threadIdx.x - off] : 0;
        __syncthreads();
        tmp[threadIdx.x] += t;
        __syncthreads();
    }
    if (gid < n) start[gid] = tmp[threadIdx.x] - v;  // exclusive
    if (threadIdx.x == SCAN_B - 1) bsum[blockIdx.x] = tmp[threadIdx.x];
}

__global__ __launch_bounds__(512) void scan2_k(int* __restrict__ bsum, int nb) {
    __shared__ int tmp[512];
    int v = (threadIdx.x < nb) ? bsum[threadIdx.x] : 0;
    tmp[threadIdx.x] = v;
    __syncthreads();
    for (int off = 1; off < 512; off <<= 1) {
        int t = (threadIdx.x >= off) ? tmp[threadIdx.x - off] : 0;
        __syncthreads();
        tmp[threadIdx.x] += t;
        __syncthreads();
    }
    if (threadIdx.x < nb) bsum[threadIdx.x] = tmp[threadIdx.x] - v;  // exclusive
}

__global__ __launch_bounds__(256) void scan3_k(int* __restrict__ start,
                                               const int* __restrict__ bsum,
                                               int n, int E) {
    int gid = blockIdx.x * blockDim.x + threadIdx.x;
    if (gid < n) start[gid] += bsum[gid / SCAN_B];
    if (gid == 0) start[n] = E;
}

// ---------------------------------------------------------------------------
// K3: fill CSR, 2 edges/thread: recompute p, alpha = p/denom[j];
// pje[start[i]+rank[k]] = {j, alpha}. No atomics; rank makes positions unique.
// ---------------------------------------------------------------------------
__global__ __launch_bounds__(256) void fill_k(
        const void* __restrict__ eidx, const int* __restrict__ flag,
        const float* __restrict__ ei_all, const float* __restrict__ ej_all,
        const float* __restrict__ denom, const int* __restrict__ start,
        const ushort* __restrict__ rank, int2* __restrict__ pje,
        long long E, long long T) {
    long long t = blockIdx.x * (long long)blockDim.x + threadIdx.x;
    if (t >= T) return;                       // tail guard (round-4 bug fix)
    int is64 = *flag;

    bool vv[2];
    int jj[2], ii[2], pos[2];
    float al[2];
    #pragma unroll
    for (int m = 0; m < 2; ++m) {
        long long k = t + (long long)m * T;
        vv[m] = (k < E);
        jj[m] = vv[m] ? load_idx(eidx, k, is64) : 0;
        ii[m] = vv[m] ? load_idx(eidx, E + k, is64) : 0;
    }
    #pragma unroll
    for (int m = 0; m < 2; ++m) {
        float e = ei_all[ii[m]] + ej_all[jj[m]];
        e = e > 0.f ? e : LEAKY * e;
        al[m] = __expf(e) / denom[jj[m]];
        pos[m] = vv[m] ? (start[ii[m]] + (int)rank[t + (long long)m * T]) : 0;
    }
    #pragma unroll
    for (int m = 0; m < 2; ++m) {
        if (vv[m]) {
            int2 ja;
            ja.x = jj[m];
            ja.y = __float_as_int(al[m]);
            pje[pos[m]] = ja;
        }
    }
}

// ---------------------------------------------------------------------------
// K4a: gather (bf16 rows): wave/node, 4 B bf16x2 per lane, 2-deep pipeline on
// the (j,alpha) pair, fused relu, single store.
// ---------------------------------------------------------------------------
__global__ __launch_bounds__(256) void gather_bf16_k(
        const int* __restrict__ start, const int2* __restrict__ pje,
        const ushort* __restrict__ xb, float* __restrict__ out, int n) {
    int wave = (int)((blockIdx.x * (long long)blockDim.x + threadIdx.x) >> 6);
    int lane = threadIdx.x & 63;
    if (wave >= n) return;
    int s = start[wave];
    int e_end = start[wave + 1];
    float ax = 0.f, ay = 0.f;
    int2 ja = make_int2(0, 0);
    if (s < e_end) ja = pje[s];
    for (int e = s; e < e_end; ++e) {
        int2 cur = ja;
        if (e + 1 < e_end) ja = pje[e + 1];      // prefetch next pair
        unsigned u = ((const unsigned*)(xb + (long long)cur.x * N_HID))[lane];
        float a  = __int_as_float(cur.y);
        float vx = __uint_as_float(u << 16);
        float vy = __uint_as_float(u & 0xffff0000u);
        ax += a * vx;
        ay += a * vy;
    }
    float2 r;
    r.x = fmaxf(ax, 0.f);
    r.y = fmaxf(ay, 0.f);
    ((float2*)(out + (long long)wave * N_HID))[lane] = r;
}

// K4b: fallback gather reading f32 x directly (if ws too small for xb).
__global__ __launch_bounds__(256) void gather_f32_k(
        const int* __restrict__ start, const int2* __restrict__ pje,
        const float* __restrict__ x, float* __restrict__ out, int n) {
    int wave = (int)((blockIdx.x * (long long)blockDim.x + threadIdx.x) >> 6);
    int lane = threadIdx.x & 63;
    if (wave >= n) return;
    int s = start[wave];
    int e_end = start[wave + 1];
    float ax = 0.f, ay = 0.f;
    int2 ja = make_int2(0, 0);
    if (s < e_end) ja = pje[s];
    for (int e = s; e < e_end; ++e) {
        int2 cur = ja;
        if (e + 1 < e_end) ja = pje[e + 1];
        float2 v = ((const float2*)(x + (long long)cur.x * N_HID))[lane];
        float a = __int_as_float(cur.y);
        ax += a * v.x;
        ay += a * v.y;
    }
    float2 r;
    r.x = fmaxf(ax, 0.f);
    r.y = fmaxf(ay, 0.f);
    ((float2*)(out + (long long)wave * N_HID))[lane] = r;
}

extern "C" void kernel_launch(void* const* d_in, const int* in_sizes, int n_in,
                              void* d_out, int out_size, void* d_ws,
                              size_t ws_size, hipStream_t stream) {
    const float* x   = (const float*)d_in[0];
    const void*  eix = d_in[1];
    const float* w_i = (const float*)d_in[2];
    const float* w_j = (const float*)d_in[3];
    float* out = (float*)d_out;

    int n = in_sizes[0] / N_HID;            // 100000
    long long E = in_sizes[1] / 2;          // 1.6M

    // ws layout (bytes, 16-aligned sections):
    //   ei[n] ej[n] denom[n] f32 | deg[n] start[n+1] bsum[512] flag[4] int
    //   rank[E] u16 | pje[E] int2 | xb[n*128] ushort (optional)
    char* p = (char*)d_ws;
    float* ei_all = (float*)p;               p += (size_t)n * 4;
    float* ej_all = (float*)p;               p += (size_t)n * 4;
    float* denom  = (float*)p;               p += (size_t)n * 4;
    int*   deg    = (int*)p;                 p += (size_t)n * 4;
    int*   start  = (int*)p;                 p += (size_t)(n + 1) * 4;
    int*   bsum   = (int*)p;                 p += 512 * 4;
    int*   flag   = (int*)p;                 p += 16;          // keep alignment
    ushort* rank  = (ushort*)p;              p += ((size_t)E * 2 + 15) & ~15ull;
    int2*  pje    = (int2*)p;                p += (size_t)E * 8;
    ushort* xb    = (ushort*)p;              p += (size_t)n * N_HID * 2;
    int wsBig = ((size_t)(p - (char*)d_ws) <= ws_size);
    if (!wsBig) xb = nullptr;

    int nb = (n + SCAN_B - 1) / SCAN_B;     // 391

    detect_dtype_k<<<1, 256, 0, stream>>>(eix, E * 2, flag);

    long long t1 = (long long)n * 64;
    node_logits_k<<<(unsigned)((t1 + 255) / 256), 256, 0, stream>>>(
        x, w_i, w_j, ei_all, ej_all, denom, deg, xb, n);

    // edge pass: 4 edges/thread
    long long T2 = (E + 3) / 4;
    edge_exp_k<<<(unsigned)((T2 + 255) / 256), 256, 0, stream>>>(
        eix, flag, ei_all, ej_all, denom, deg, rank, E, T2);

    scan1_k<<<nb, SCAN_B, 0, stream>>>(deg, start, bsum, n);
    scan2_k<<<1, 512, 0, stream>>>(bsum, nb);
    scan3_k<<<nb, SCAN_B, 0, stream>>>(start, bsum, n, (int)E);

    // fill pass: 2 edges/thread
    long long T3 = (E + 1) / 2;
    fill_k<<<(unsigned)((T3 + 255) / 256), 256, 0, stream>>>(
        eix, flag, ei_all, ej_all, denom, start, rank, pje, E, T3);

    long long t4 = (long long)n * 64;
    if (wsBig) {
        gather_bf16_k<<<(unsigned)((t4 + 255) / 256), 256, 0, stream>>>(
            start, pje, xb, out, n);
    } else {
        gather_f32_k<<<(unsigned)((t4 + 255) / 256), 256, 0, stream>>>(
            start, pje, x, out, n);
    }
}

// Round 6
// 322.566 us; speedup vs baseline: 1.0640x; 1.0640x over previous
//
#include <hip/hip_runtime.h>

#define N_HID 128
#define LEAKY 0.01f
#define SCAN_B 256
#define NXCD 8

// ---------------------------------------------------------------------------
// helpers
// ---------------------------------------------------------------------------
__device__ inline ushort f2bf_rne(float f) {   // f32 -> bf16, round-nearest-even
    unsigned u = __float_as_uint(f);
    u += 0x7fffu + ((u >> 16) & 1u);
    return (ushort)(u >> 16);
}

__device__ inline int load_idx(const void* eidx, long long pos, int is64) {
    if (is64) return (int)((const long long*)eidx)[pos];
    return ((const int*)eidx)[pos];
}

// Physical XCD id (0..7). hwreg 20 = HW_REG_XCC_ID on gfx94x/gfx950
// (HW-verified on MI355X, learn_hip m09). Wave-uniform SGPR read.
__device__ inline unsigned xcd_id() {
    unsigned x;
    asm volatile("s_getreg_b32 %0, hwreg(20, 0, 4)" : "=s"(x));
    return x & (NXCD - 1);
}

// ---------------------------------------------------------------------------
// K0: detect int64 vs int32 edge_index.
// ---------------------------------------------------------------------------
__global__ void detect_dtype_k(const void* __restrict__ eidx, long long n_i64,
                               int* __restrict__ flag) {
    __shared__ int nonzero_hi;
    if (threadIdx.x == 0) nonzero_hi = 0;
    __syncthreads();
    const long long* p = (const long long*)eidx;
    long long samples = n_i64 < 4096 ? n_i64 : 4096;
    int bad = 0;
    for (long long k = threadIdx.x; k < samples; k += blockDim.x) {
        if ((p[k] >> 32) != 0) bad = 1;
    }
    if (bad) atomicOr(&nonzero_hi, 1);
    __syncthreads();
    if (threadIdx.x == 0) *flag = nonzero_hi ? 0 : 1;  // 1 => int64
}

// ---------------------------------------------------------------------------
// K1: per-node logits ei = x.w_i, ej = x.w_j (wave/node, shfl reduce).
// Fused: bf16-quantize the x row into xb.
// ---------------------------------------------------------------------------
__global__ __launch_bounds__(256) void node_logits_k(
        const float* __restrict__ x, const float* __restrict__ w_i,
        const float* __restrict__ w_j, float* __restrict__ ei_all,
        float* __restrict__ ej_all, ushort* __restrict__ xb, int n) {
    int wave = (int)((blockIdx.x * (long long)blockDim.x + threadIdx.x) >> 6);
    int lane = threadIdx.x & 63;
    if (wave >= n) return;
    const float2* xr = (const float2*)(x + (long long)wave * N_HID);
    float2 v  = xr[lane];
    float2 wi = ((const float2*)w_i)[lane];
    float2 wj = ((const float2*)w_j)[lane];
    if (xb) {
        unsigned packed = (unsigned)f2bf_rne(v.x) | ((unsigned)f2bf_rne(v.y) << 16);
        ((unsigned*)(xb + (long long)wave * N_HID))[lane] = packed;
    }
    float si = v.x * wi.x + v.y * wi.y;
    float sj = v.x * wj.x + v.y * wj.y;
    #pragma unroll
    for (int off = 32; off >= 1; off >>= 1) {
        si += __shfl_xor(si, off);
        sj += __shfl_xor(sj, off);
    }
    if (lane == 0) {
        ei_all[wave] = si;
        ej_all[wave] = sj;
    }
}

// ---------------------------------------------------------------------------
// K2: per-edge: p = exp(leaky(ei[i]+ej[j])) in fixed-point (x8192);
//   denom_part[xcd][j] += p_fix   (XCD-private, workgroup-scope -> L2-side)
//   lrank = deg_part[xcd][i]++    (ditto)
//   rank[k] = xcd<<12 | lrank
// Integer partials: exact, order-independent, native atomics.
// leaky_relu bounds e in [-0.12, ~7.4] -> p in [0.887, ~1800]; p_fix <= 1.5e7,
// per-(xcd,j) sums < 2^30: no overflow, denom quant rel-err <= 7e-5.
// ---------------------------------------------------------------------------
__global__ __launch_bounds__(256) void edge_exp_k(
        const void* __restrict__ eidx, const int* __restrict__ flag,
        const float* __restrict__ ei_all, const float* __restrict__ ej_all,
        unsigned* __restrict__ denom_part, unsigned* __restrict__ deg_part,
        ushort* __restrict__ rank, long long E, int n) {
    long long k = blockIdx.x * (long long)blockDim.x + threadIdx.x;
    if (k >= E) return;
    int is64 = *flag;
    unsigned xcd = xcd_id();
    int j = load_idx(eidx, k, is64);       // softmax group (source)
    int i = load_idx(eidx, E + k, is64);   // destination
    float e = ei_all[i] + ej_all[j];
    e = e > 0.f ? e : LEAKY * e;
    unsigned pf = __float2uint_rn(__expf(e) * 8192.f);
    __hip_atomic_fetch_add(&denom_part[(size_t)xcd * n + j], pf,
                           __ATOMIC_RELAXED, __HIP_MEMORY_SCOPE_WORKGROUP);
    unsigned r = __hip_atomic_fetch_add(&deg_part[(size_t)xcd * n + i], 1u,
                                        __ATOMIC_RELAXED, __HIP_MEMORY_SCOPE_WORKGROUP);
    rank[k] = (ushort)((xcd << 12) | (r & 0xFFFu));
}

// ---------------------------------------------------------------------------
// Scan stage 1: per node, fold 8 XCD partials:
//   xbase[x][i] = sum_{x'<x} deg_part[x'][i]  (u16)
//   dtot        = sum_x deg_part[x][i]
//   denomf[i]   = (sum_x denom_part[x][i]) / 8192
// then exclusive block-scan of dtot -> start, block totals -> bsum.
// ---------------------------------------------------------------------------
__global__ __launch_bounds__(SCAN_B) void scan1_k(
        const unsigned* __restrict__ deg_part,
        const unsigned* __restrict__ denom_part,
        ushort* __restrict__ xbase, float* __restrict__ denomf,
        int* __restrict__ start, int* __restrict__ bsum, int n) {
    __shared__ int tmp[SCAN_B];
    int gid = blockIdx.x * SCAN_B + threadIdx.x;
    int dtot = 0;
    if (gid < n) {
        unsigned c = 0, s = 0;
        #pragma unroll
        for (int x = 0; x < NXCD; ++x) {
            xbase[(size_t)x * n + gid] = (ushort)c;
            c += deg_part[(size_t)x * n + gid];
            s += denom_part[(size_t)x * n + gid];
        }
        dtot = (int)c;
        denomf[gid] = (float)s * (1.f / 8192.f);
    }
    tmp[threadIdx.x] = dtot;
    __syncthreads();
    for (int off = 1; off < SCAN_B; off <<= 1) {
        int t = (threadIdx.x >= off) ? tmp[threadIdx.x - off] : 0;
        __syncthreads();
        tmp[threadIdx.x] += t;
        __syncthreads();
    }
    if (gid < n) start[gid] = tmp[threadIdx.x] - dtot;  // exclusive
    if (threadIdx.x == SCAN_B - 1) bsum[blockIdx.x] = tmp[threadIdx.x];
}

__global__ __launch_bounds__(512) void scan2_k(int* __restrict__ bsum, int nb) {
    __shared__ int tmp[512];
    int v = (threadIdx.x < nb) ? bsum[threadIdx.x] : 0;
    tmp[threadIdx.x] = v;
    __syncthreads();
    for (int off = 1; off < 512; off <<= 1) {
        int t = (threadIdx.x >= off) ? tmp[threadIdx.x - off] : 0;
        __syncthreads();
        tmp[threadIdx.x] += t;
        __syncthreads();
    }
    if (threadIdx.x < nb) bsum[threadIdx.x] = tmp[threadIdx.x] - v;  // exclusive
}

__global__ __launch_bounds__(256) void scan3_k(int* __restrict__ start,
                                               const int* __restrict__ bsum,
                                               int n, int E) {
    int gid = blockIdx.x * blockDim.x + threadIdx.x;
    if (gid < n) start[gid] += bsum[gid / SCAN_B];
    if (gid == 0) start[n] = E;
}

// ---------------------------------------------------------------------------
// K3: fill CSR: alpha = p/denomf[j]; slot = start[i] + xbase[xcd][i] + lrank;
// pje[slot] = j<<15 | round(alpha*32768) (clamped). Single 4B scattered store,
// plain (non-atomic) -> L2 write-combined. alpha-quant err <= 2e-5.
// ---------------------------------------------------------------------------
__global__ __launch_bounds__(256) void fill_k(
        const void* __restrict__ eidx, const int* __restrict__ flag,
        const float* __restrict__ ei_all, const float* __restrict__ ej_all,
        const float* __restrict__ denomf, const int* __restrict__ start,
        const ushort* __restrict__ xbase, const ushort* __restrict__ rank,
        unsigned* __restrict__ pje, long long E, int n) {
    long long k = blockIdx.x * (long long)blockDim.x + threadIdx.x;
    if (k >= E) return;
    int is64 = *flag;
    int j = load_idx(eidx, k, is64);
    int i = load_idx(eidx, E + k, is64);
    float e = ei_all[i] + ej_all[j];
    e = e > 0.f ? e : LEAKY * e;
    float alpha = __expf(e) / denomf[j];
    unsigned aq = __float2uint_rn(alpha * 32768.f);
    if (aq > 32767u) aq = 32767u;
    ushort rk = rank[k];
    int xcd = rk >> 12;
    int lrank = rk & 0xFFF;
    int slot = start[i] + (int)xbase[(size_t)xcd * n + i] + lrank;
    pje[slot] = ((unsigned)j << 15) | aq;
}

// ---------------------------------------------------------------------------
// K4a: gather (bf16 rows): wave/node, 4B bf16x2 per lane, 2-deep pipeline on
// the packed (j,alpha) word, fused relu, single store.
// ---------------------------------------------------------------------------
__global__ __launch_bounds__(256) void gather_bf16_k(
        const int* __restrict__ start, const unsigned* __restrict__ pje,
        const ushort* __restrict__ xb, float* __restrict__ out, int n) {
    int wave = (int)((blockIdx.x * (long long)blockDim.x + threadIdx.x) >> 6);
    int lane = threadIdx.x & 63;
    if (wave >= n) return;
    int s = start[wave];
    int e_end = start[wave + 1];
    float ax = 0.f, ay = 0.f;
    unsigned ja = 0;
    if (s < e_end) ja = pje[s];
    for (int e = s; e < e_end; ++e) {
        unsigned cur = ja;
        if (e + 1 < e_end) ja = pje[e + 1];      // prefetch next pair
        float a = (float)(cur & 0x7FFFu) * (1.f / 32768.f);
        unsigned u = ((const unsigned*)(xb + (long long)(cur >> 15) * N_HID))[lane];
        float vx = __uint_as_float(u << 16);
        float vy = __uint_as_float(u & 0xffff0000u);
        ax += a * vx;
        ay += a * vy;
    }
    float2 r;
    r.x = fmaxf(ax, 0.f);
    r.y = fmaxf(ay, 0.f);
    ((float2*)(out + (long long)wave * N_HID))[lane] = r;
}

// K4b: fallback gather reading f32 x directly (if ws too small for xb).
__global__ __launch_bounds__(256) void gather_f32_k(
        const int* __restrict__ start, const unsigned* __restrict__ pje,
        const float* __restrict__ x, float* __restrict__ out, int n) {
    int wave = (int)((blockIdx.x * (long long)blockDim.x + threadIdx.x) >> 6);
    int lane = threadIdx.x & 63;
    if (wave >= n) return;
    int s = start[wave];
    int e_end = start[wave + 1];
    float ax = 0.f, ay = 0.f;
    unsigned ja = 0;
    if (s < e_end) ja = pje[s];
    for (int e = s; e < e_end; ++e) {
        unsigned cur = ja;
        if (e + 1 < e_end) ja = pje[e + 1];
        float a = (float)(cur & 0x7FFFu) * (1.f / 32768.f);
        float2 v = ((const float2*)(x + (long long)(cur >> 15) * N_HID))[lane];
        ax += a * v.x;
        ay += a * v.y;
    }
    float2 r;
    r.x = fmaxf(ax, 0.f);
    r.y = fmaxf(ay, 0.f);
    ((float2*)(out + (long long)wave * N_HID))[lane] = r;
}

extern "C" void kernel_launch(void* const* d_in, const int* in_sizes, int n_in,
                              void* d_out, int out_size, void* d_ws,
                              size_t ws_size, hipStream_t stream) {
    const float* x   = (const float*)d_in[0];
    const void*  eix = d_in[1];
    const float* w_i = (const float*)d_in[2];
    const float* w_j = (const float*)d_in[3];
    float* out = (float*)d_out;

    int n = in_sizes[0] / N_HID;            // 100000
    long long E = in_sizes[1] / 2;          // 1.6M

    // ws layout (bytes):
    //   ei[n] ej[n] denomf[n] f32 | start[n+1] bsum[512] flag int
    //   xbase[8n] u16 | rank[E] u16 | pje[E] u32
    //   parts[16n] u32 (denom_part[8n], deg_part[8n])
    //   xb[n*128] u16 (optional)                            total ~44.8 MB
    char* p = (char*)d_ws;
    float* ei_all = (float*)p;               p += (size_t)n * 4;
    float* ej_all = (float*)p;               p += (size_t)n * 4;
    float* denomf = (float*)p;               p += (size_t)n * 4;
    int*   start  = (int*)p;                 p += ((size_t)(n + 1) * 4 + 15) & ~15ull;
    int*   bsum   = (int*)p;                 p += 512 * 4;
    int*   flag   = (int*)p;                 p += 16;
    ushort* xbase = (ushort*)p;              p += (size_t)NXCD * n * 2;
    ushort* rank  = (ushort*)p;              p += ((size_t)E * 2 + 15) & ~15ull;
    unsigned* pje = (unsigned*)p;            p += (size_t)E * 4;
    unsigned* denom_part = (unsigned*)p;     p += (size_t)NXCD * n * 4;
    unsigned* deg_part   = (unsigned*)p;     p += (size_t)NXCD * n * 4;
    ushort* xb    = (ushort*)p;              p += (size_t)n * N_HID * 2;
    int wsBig = ((size_t)(p - (char*)d_ws) <= ws_size);
    if (!wsBig) xb = nullptr;

    int nb = (n + SCAN_B - 1) / SCAN_B;     // 391

    // zero the XCD partials (graph-replay safe)
    hipMemsetAsync(denom_part, 0, (size_t)2 * NXCD * n * 4, stream);

    detect_dtype_k<<<1, 256, 0, stream>>>(eix, E * 2, flag);

    long long t1 = (long long)n * 64;
    node_logits_k<<<(unsigned)((t1 + 255) / 256), 256, 0, stream>>>(
        x, w_i, w_j, ei_all, ej_all, xb, n);

    edge_exp_k<<<(unsigned)((E + 255) / 256), 256, 0, stream>>>(
        eix, flag, ei_all, ej_all, denom_part, deg_part, rank, E, n);

    scan1_k<<<nb, SCAN_B, 0, stream>>>(deg_part, denom_part, xbase, denomf,
                                       start, bsum, n);
    scan2_k<<<1, 512, 0, stream>>>(bsum, nb);
    scan3_k<<<nb, SCAN_B, 0, stream>>>(start, bsum, n, (int)E);

    fill_k<<<(unsigned)((E + 255) / 256), 256, 0, stream>>>(
        eix, flag, ei_all, ej_all, denomf, start, xbase, rank, pje, E, n);

    long long t4 = (long long)n * 64;
    if (wsBig) {
        gather_bf16_k<<<(unsigned)((t4 + 255) / 256), 256, 0, stream>>>(
            start, pje, xb, out, n);
    } else {
        gather_f32_k<<<(unsigned)((t4 + 255) / 256), 256, 0, stream>>>(
            start, pje, x, out, n);
    }
}

// Round 7
// 284.160 us; speedup vs baseline: 1.2078x; 1.1352x over previous
//
#include <hip/hip_runtime.h>

#define N_HID 128
#define LEAKY 0.01f
#define EPB   4096      // edges per block in passA/scatter (256 thr x 16)
#define SCB   512       // table-scan block size

// ---------------------------------------------------------------------------
// helpers
// ---------------------------------------------------------------------------
__device__ inline ushort f2bf_rne(float f) {   // f32 -> bf16, round-nearest-even
    unsigned u = __float_as_uint(f);
    u += 0x7fffu + ((u >> 16) & 1u);
    return (ushort)(u >> 16);
}

__device__ inline int load_idx(const void* eidx, long long pos, int is64) {
    if (is64) return (int)((const long long*)eidx)[pos];
    return ((const int*)eidx)[pos];
}

// ---------------------------------------------------------------------------
// K0: detect int64 vs int32 edge_index.
// ---------------------------------------------------------------------------
__global__ void detect_dtype_k(const void* __restrict__ eidx, long long n_i64,
                               int* __restrict__ flag) {
    __shared__ int nonzero_hi;
    if (threadIdx.x == 0) nonzero_hi = 0;
    __syncthreads();
    const long long* p = (const long long*)eidx;
    long long samples = n_i64 < 4096 ? n_i64 : 4096;
    int bad = 0;
    for (long long k = threadIdx.x; k < samples; k += blockDim.x) {
        if ((p[k] >> 32) != 0) bad = 1;
    }
    if (bad) atomicOr(&nonzero_hi, 1);
    __syncthreads();
    if (threadIdx.x == 0) *flag = nonzero_hi ? 0 : 1;  // 1 => int64
}

// ---------------------------------------------------------------------------
// K1: per-node logits ei = x.w_i, ej = x.w_j (wave/node, shfl reduce).
// Fused: bf16-quantize the x row into xb.
// ---------------------------------------------------------------------------
__global__ __launch_bounds__(256) void node_logits_k(
        const float* __restrict__ x, const float* __restrict__ w_i,
        const float* __restrict__ w_j, float* __restrict__ ei_all,
        float* __restrict__ ej_all, ushort* __restrict__ xb, int n) {
    int wave = (int)((blockIdx.x * (long long)blockDim.x + threadIdx.x) >> 6);
    int lane = threadIdx.x & 63;
    if (wave >= n) return;
    const float2* xr = (const float2*)(x + (long long)wave * N_HID);
    float2 v  = xr[lane];
    float2 wi = ((const float2*)w_i)[lane];
    float2 wj = ((const float2*)w_j)[lane];
    if (xb) {
        unsigned packed = (unsigned)f2bf_rne(v.x) | ((unsigned)f2bf_rne(v.y) << 16);
        ((unsigned*)(xb + (long long)wave * N_HID))[lane] = packed;
    }
    float si = v.x * wi.x + v.y * wi.y;
    float sj = v.x * wj.x + v.y * wj.y;
    #pragma unroll
    for (int off = 32; off >= 1; off >>= 1) {
        si += __shfl_xor(si, off);
        sj += __shfl_xor(sj, off);
    }
    if (lane == 0) {
        ei_all[wave] = si;
        ej_all[wave] = sj;
    }
}

// ---------------------------------------------------------------------------
// K2 (passA): per-edge p = exp(leaky(ei[i]+ej[j])); denom[j] += p (the ONLY
// global atomics left, 1.6M sectors); LDS histogram of coarse bucket (i>>8);
// per-block counts -> tab[bucket][block]. Segment-max skipped: |e| <= ~8 so
// exp stays comfortably in f32 range and the max cancels in the ratio.
// ---------------------------------------------------------------------------
__global__ __launch_bounds__(256) void passA_k(
        const void* __restrict__ eidx, const int* __restrict__ flag,
        const float* __restrict__ ei_all, const float* __restrict__ ej_all,
        float* __restrict__ denom, unsigned* __restrict__ tab,
        long long E, int nblkA, int NB) {
    __shared__ unsigned hist[512];
    for (int b = threadIdx.x; b < NB; b += 256) hist[b] = 0;
    __syncthreads();
    int is64 = *flag;
    long long k0 = (long long)blockIdx.x * EPB;
    #pragma unroll 4
    for (int m = 0; m < EPB / 256; ++m) {
        long long k = k0 + m * 256 + threadIdx.x;
        if (k < E) {
            int j = load_idx(eidx, k, is64);       // softmax group (source)
            int i = load_idx(eidx, E + k, is64);   // destination
            float e = ei_all[i] + ej_all[j];
            e = e > 0.f ? e : LEAKY * e;
            float p = __expf(e);
            unsafeAtomicAdd(&denom[j], p);         // native f32 atomic
            atomicAdd(&hist[i >> 8], 1u);          // LDS atomic
        }
    }
    __syncthreads();
    for (int b = threadIdx.x; b < NB; b += 256)
        tab[(size_t)b * nblkA + blockIdx.x] = hist[b];
}

// ---------------------------------------------------------------------------
// Exclusive scan over the [NB][nblkA] table (bucket-major), 3 kernels.
// NT = NB*nblkA ~ 153k; nb1 = ceil(NT/512) ~ 299 <= 512.
// ---------------------------------------------------------------------------
__global__ __launch_bounds__(SCB) void scanT1_k(unsigned* __restrict__ a,
                                                unsigned* __restrict__ bs, int nt) {
    __shared__ unsigned tmp[SCB];
    int gid = blockIdx.x * SCB + threadIdx.x;
    unsigned v = (gid < nt) ? a[gid] : 0;
    tmp[threadIdx.x] = v;
    __syncthreads();
    for (int off = 1; off < SCB; off <<= 1) {
        unsigned t = (threadIdx.x >= off) ? tmp[threadIdx.x - off] : 0;
        __syncthreads();
        tmp[threadIdx.x] += t;
        __syncthreads();
    }
    if (gid < nt) a[gid] = tmp[threadIdx.x] - v;   // exclusive
    if (threadIdx.x == SCB - 1) bs[blockIdx.x] = tmp[threadIdx.x];
}

__global__ __launch_bounds__(SCB) void scanT2_k(unsigned* __restrict__ bs, int nb) {
    __shared__ unsigned tmp[SCB];
    unsigned v = (threadIdx.x < nb) ? bs[threadIdx.x] : 0;
    tmp[threadIdx.x] = v;
    __syncthreads();
    for (int off = 1; off < SCB; off <<= 1) {
        unsigned t = (threadIdx.x >= off) ? tmp[threadIdx.x - off] : 0;
        __syncthreads();
        tmp[threadIdx.x] += t;
        __syncthreads();
    }
    if (threadIdx.x < nb) bs[threadIdx.x] = tmp[threadIdx.x] - v;  // exclusive
}

__global__ __launch_bounds__(SCB) void scanT3_k(unsigned* __restrict__ a,
                                                const unsigned* __restrict__ bs,
                                                int nt) {
    int gid = blockIdx.x * SCB + threadIdx.x;
    if (gid < nt) a[gid] += bs[gid / SCB];
}

// ---------------------------------------------------------------------------
// K3 (scatter): same block<->edge mapping as passA. Places packed u32 record
// (i&255)<<17 | j into its bucket region via LDS cursors. No global atomics.
// ---------------------------------------------------------------------------
__global__ __launch_bounds__(256) void scatter_k(
        const void* __restrict__ eidx, const int* __restrict__ flag,
        const unsigned* __restrict__ tab, unsigned* __restrict__ srec,
        long long E, int nblkA, int NB) {
    __shared__ unsigned cur[512];
    for (int b = threadIdx.x; b < NB; b += 256)
        cur[b] = tab[(size_t)b * nblkA + blockIdx.x];
    __syncthreads();
    int is64 = *flag;
    long long k0 = (long long)blockIdx.x * EPB;
    #pragma unroll 4
    for (int m = 0; m < EPB / 256; ++m) {
        long long k = k0 + m * 256 + threadIdx.x;
        if (k < E) {
            int j = load_idx(eidx, k, is64);
            int i = load_idx(eidx, E + k, is64);
            unsigned pos = atomicAdd(&cur[i >> 8], 1u);   // LDS atomic
            srec[pos] = ((unsigned)(i & 255) << 17) | (unsigned)j;
        }
    }
}

// ---------------------------------------------------------------------------
// K4 (finalize): one workgroup per bucket (256 nodes). LDS per-node counts +
// scan -> exact CSR start[]; recompute p, alpha = p/denom[j]; LDS-ranked slot;
// pje[slot] = j<<15 | round(alpha*32768). Replaces fill/rank entirely.
// ---------------------------------------------------------------------------
__global__ __launch_bounds__(256) void finalize_k(
        const unsigned* __restrict__ srec, const unsigned* __restrict__ tab,
        const float* __restrict__ ei_all, const float* __restrict__ ej_all,
        const float* __restrict__ denom, int* __restrict__ start,
        unsigned* __restrict__ pje, int n, long long E, int nblkA, int NB) {
    int b = blockIdx.x;
    int tid = threadIdx.x;
    int base = (int)tab[(size_t)b * nblkA];
    int end  = (b + 1 < NB) ? (int)tab[(size_t)(b + 1) * nblkA] : (int)E;

    __shared__ int cnt[256];
    __shared__ int off[256];
    __shared__ float eil[256];
    int g = b * 256 + tid;
    cnt[tid] = 0;
    eil[tid] = (g < n) ? ei_all[g] : 0.f;
    __syncthreads();

    for (int t = base + tid; t < end; t += 256)
        atomicAdd(&cnt[srec[t] >> 17], 1);
    __syncthreads();

    // exclusive scan of cnt -> per-node local offsets
    int v = cnt[tid];
    off[tid] = v;
    __syncthreads();
    for (int s = 1; s < 256; s <<= 1) {
        int t2 = (tid >= s) ? off[tid - s] : 0;
        __syncthreads();
        off[tid] += t2;
        __syncthreads();
    }
    int excl = off[tid] - v;
    if (g < n) start[g] = base + excl;
    if (b == NB - 1 && tid == 0) start[n] = (int)E;

    cnt[tid] = excl;   // reuse as cursor
    __syncthreads();

    for (int t = base + tid; t < end; t += 256) {
        unsigned r = srec[t];
        int il = (int)(r >> 17);
        int j  = (int)(r & 0x1FFFFu);
        float e = eil[il] + ej_all[j];
        e = e > 0.f ? e : LEAKY * e;
        float alpha = __expf(e) / denom[j];
        unsigned aq = __float2uint_rn(alpha * 32768.f);
        if (aq > 32767u) aq = 32767u;
        int slot = base + atomicAdd(&cnt[il], 1);
        pje[slot] = ((unsigned)j << 15) | aq;
    }
}

// ---------------------------------------------------------------------------
// K5a: gather (bf16 rows): wave/node, 4B bf16x2 per lane, 2-deep pipeline on
// the packed (j,alpha) word, fused relu, single store.
// ---------------------------------------------------------------------------
__global__ __launch_bounds__(256) void gather_bf16_k(
        const int* __restrict__ start, const unsigned* __restrict__ pje,
        const ushort* __restrict__ xb, float* __restrict__ out, int n) {
    int wave = (int)((blockIdx.x * (long long)blockDim.x + threadIdx.x) >> 6);
    int lane = threadIdx.x & 63;
    if (wave >= n) return;
    int s = start[wave];
    int e_end = start[wave + 1];
    float ax = 0.f, ay = 0.f;
    unsigned ja = 0;
    if (s < e_end) ja = pje[s];
    for (int e = s; e < e_end; ++e) {
        unsigned cur = ja;
        if (e + 1 < e_end) ja = pje[e + 1];      // prefetch next pair
        float a = (float)(cur & 0x7FFFu) * (1.f / 32768.f);
        unsigned u = ((const unsigned*)(xb + (long long)(cur >> 15) * N_HID))[lane];
        float vx = __uint_as_float(u << 16);
        float vy = __uint_as_float(u & 0xffff0000u);
        ax += a * vx;
        ay += a * vy;
    }
    float2 r;
    r.x = fmaxf(ax, 0.f);
    r.y = fmaxf(ay, 0.f);
    ((float2*)(out + (long long)wave * N_HID))[lane] = r;
}

// K5b: fallback gather reading f32 x directly (if ws too small for xb).
__global__ __launch_bounds__(256) void gather_f32_k(
        const int* __restrict__ start, const unsigned* __restrict__ pje,
        const float* __restrict__ x, float* __restrict__ out, int n) {
    int wave = (int)((blockIdx.x * (long long)blockDim.x + threadIdx.x) >> 6);
    int lane = threadIdx.x & 63;
    if (wave >= n) return;
    int s = start[wave];
    int e_end = start[wave + 1];
    float ax = 0.f, ay = 0.f;
    unsigned ja = 0;
    if (s < e_end) ja = pje[s];
    for (int e = s; e < e_end; ++e) {
        unsigned cur = ja;
        if (e + 1 < e_end) ja = pje[e + 1];
        float a = (float)(cur & 0x7FFFu) * (1.f / 32768.f);
        float2 v = ((const float2*)(x + (long long)(cur >> 15) * N_HID))[lane];
        ax += a * v.x;
        ay += a * v.y;
    }
    float2 r;
    r.x = fmaxf(ax, 0.f);
    r.y = fmaxf(ay, 0.f);
    ((float2*)(out + (long long)wave * N_HID))[lane] = r;
}

extern "C" void kernel_launch(void* const* d_in, const int* in_sizes, int n_in,
                              void* d_out, int out_size, void* d_ws,
                              size_t ws_size, hipStream_t stream) {
    const float* x   = (const float*)d_in[0];
    const void*  eix = d_in[1];
    const float* w_i = (const float*)d_in[2];
    const float* w_j = (const float*)d_in[3];
    float* out = (float*)d_out;

    int n = in_sizes[0] / N_HID;            // 100000
    long long E = in_sizes[1] / 2;          // 1.6M

    int nblkA = (int)((E + EPB - 1) / EPB); // 391
    int NB    = (n + 255) / 256;            // 391 (<= 512 required)
    int NT    = NB * nblkA;                 // ~153k
    int nb1   = (NT + SCB - 1) / SCB;       // ~299 (<= 512 required)

    // ws layout (bytes):
    //   ei[n] ej[n] denom[n] f32 | start[n+1] int | tab[NT] u32 | bs1[512] u32
    //   flag | srec[E] u32 | pje[E] u32 | xb[n*128] u16 (optional)  ~40.7 MB
    char* p = (char*)d_ws;
    float* ei_all = (float*)p;               p += (size_t)n * 4;
    float* ej_all = (float*)p;               p += (size_t)n * 4;
    float* denom  = (float*)p;               p += (size_t)n * 4;
    int*   start  = (int*)p;                 p += ((size_t)(n + 1) * 4 + 15) & ~15ull;
    unsigned* tab = (unsigned*)p;            p += ((size_t)NT * 4 + 15) & ~15ull;
    unsigned* bs1 = (unsigned*)p;            p += (size_t)SCB * 4;
    int*   flag   = (int*)p;                 p += 16;
    unsigned* srec = (unsigned*)p;           p += (size_t)E * 4;
    unsigned* pje  = (unsigned*)p;           p += (size_t)E * 4;
    ushort* xb    = (ushort*)p;              p += (size_t)n * N_HID * 2;
    int wsBig = ((size_t)(p - (char*)d_ws) <= ws_size);
    if (!wsBig) xb = nullptr;

    hipMemsetAsync(denom, 0, (size_t)n * 4, stream);

    detect_dtype_k<<<1, 256, 0, stream>>>(eix, E * 2, flag);

    long long t1 = (long long)n * 64;
    node_logits_k<<<(unsigned)((t1 + 255) / 256), 256, 0, stream>>>(
        x, w_i, w_j, ei_all, ej_all, xb, n);

    passA_k<<<nblkA, 256, 0, stream>>>(eix, flag, ei_all, ej_all, denom, tab,
                                       E, nblkA, NB);

    scanT1_k<<<nb1, SCB, 0, stream>>>(tab, bs1, NT);
    scanT2_k<<<1, SCB, 0, stream>>>(bs1, nb1);
    scanT3_k<<<nb1, SCB, 0, stream>>>(tab, bs1, NT);

    scatter_k<<<nblkA, 256, 0, stream>>>(eix, flag, tab, srec, E, nblkA, NB);

    finalize_k<<<NB, 256, 0, stream>>>(srec, tab, ei_all, ej_all, denom,
                                       start, pje, n, E, nblkA, NB);

    long long t4 = (long long)n * 64;
    if (wsBig) {
        gather_bf16_k<<<(unsigned)((t4 + 255) / 256), 256, 0, stream>>>(
            start, pje, xb, out, n);
    } else {
        gather_f32_k<<<(unsigned)((t4 + 255) / 256), 256, 0, stream>>>(
            start, pje, x, out, n);
    }
}

// Round 8
// 238.994 us; speedup vs baseline: 1.4361x; 1.1890x over previous
//
#include <hip/hip_runtime.h>

#define N_HID 128
#define LEAKY 0.01f
#define EPB   4096      // edges per block in hist/scatter (256 thr x 16)
#define SCB   512       // table-scan block size

// ---------------------------------------------------------------------------
// helpers
// ---------------------------------------------------------------------------
__device__ inline ushort f2bf_rne(float f) {   // f32 -> bf16, round-nearest-even
    unsigned u = __float_as_uint(f);
    u += 0x7fffu + ((u >> 16) & 1u);
    return (ushort)(u >> 16);
}

__device__ inline int load_idx(const void* eidx, long long pos, int is64) {
    if (is64) return (int)((const long long*)eidx)[pos];
    return ((const int*)eidx)[pos];
}

// ---------------------------------------------------------------------------
// K0: detect int64 vs int32 edge_index.
// ---------------------------------------------------------------------------
__global__ void detect_dtype_k(const void* __restrict__ eidx, long long n_i64,
                               int* __restrict__ flag) {
    __shared__ int nonzero_hi;
    if (threadIdx.x == 0) nonzero_hi = 0;
    __syncthreads();
    const long long* p = (const long long*)eidx;
    long long samples = n_i64 < 4096 ? n_i64 : 4096;
    int bad = 0;
    for (long long k = threadIdx.x; k < samples; k += blockDim.x) {
        if ((p[k] >> 32) != 0) bad = 1;
    }
    if (bad) atomicOr(&nonzero_hi, 1);
    __syncthreads();
    if (threadIdx.x == 0) *flag = nonzero_hi ? 0 : 1;  // 1 => int64
}

// ---------------------------------------------------------------------------
// K1: per-node logits ei = x.w_i, ej = x.w_j (wave/node, shfl reduce).
// Fused: bf16-quantize the x row into xb.
// ---------------------------------------------------------------------------
__global__ __launch_bounds__(256) void node_logits_k(
        const float* __restrict__ x, const float* __restrict__ w_i,
        const float* __restrict__ w_j, float* __restrict__ ei_all,
        float* __restrict__ ej_all, ushort* __restrict__ xb, int n) {
    int wave = (int)((blockIdx.x * (long long)blockDim.x + threadIdx.x) >> 6);
    int lane = threadIdx.x & 63;
    if (wave >= n) return;
    const float2* xr = (const float2*)(x + (long long)wave * N_HID);
    float2 v  = xr[lane];
    float2 wi = ((const float2*)w_i)[lane];
    float2 wj = ((const float2*)w_j)[lane];
    if (xb) {
        unsigned packed = (unsigned)f2bf_rne(v.x) | ((unsigned)f2bf_rne(v.y) << 16);
        ((unsigned*)(xb + (long long)wave * N_HID))[lane] = packed;
    }
    float si = v.x * wi.x + v.y * wi.y;
    float sj = v.x * wj.x + v.y * wj.y;
    #pragma unroll
    for (int off = 32; off >= 1; off >>= 1) {
        si += __shfl_xor(si, off);
        sj += __shfl_xor(sj, off);
    }
    if (lane == 0) {
        ei_all[wave] = si;
        ej_all[wave] = sj;
    }
}

// ---------------------------------------------------------------------------
// K2 (hist): one pass over edges; LDS histograms of BOTH coarse buckets
// (i>>8 and j>>8). No global atomics.
// ---------------------------------------------------------------------------
__global__ __launch_bounds__(256) void hist_k(
        const void* __restrict__ eidx, const int* __restrict__ flag,
        unsigned* __restrict__ tabI, unsigned* __restrict__ tabJ,
        long long E, int nblkA, int NB) {
    __shared__ unsigned hi[512], hj[512];
    for (int b = threadIdx.x; b < NB; b += 256) { hi[b] = 0; hj[b] = 0; }
    __syncthreads();
    int is64 = *flag;
    long long k0 = (long long)blockIdx.x * EPB;
    #pragma unroll 4
    for (int m = 0; m < EPB / 256; ++m) {
        long long k = k0 + m * 256 + threadIdx.x;
        if (k < E) {
            int j = load_idx(eidx, k, is64);       // softmax group (source)
            int i = load_idx(eidx, E + k, is64);   // destination
            atomicAdd(&hi[i >> 8], 1u);            // LDS atomics only
            atomicAdd(&hj[j >> 8], 1u);
        }
    }
    __syncthreads();
    for (int b = threadIdx.x; b < NB; b += 256) {
        tabI[(size_t)b * nblkA + blockIdx.x] = hi[b];
        tabJ[(size_t)b * nblkA + blockIdx.x] = hj[b];
    }
}

// ---------------------------------------------------------------------------
// Exclusive scan over a [NB][nblkA] table (bucket-major), 3 kernels.
// NT = NB*nblkA ~ 153k; nb1 = ceil(NT/512) ~ 299 <= 512. Run once per table.
// ---------------------------------------------------------------------------
__global__ __launch_bounds__(SCB) void scanT1_k(unsigned* __restrict__ a,
                                                unsigned* __restrict__ bs, int nt) {
    __shared__ unsigned tmp[SCB];
    int gid = blockIdx.x * SCB + threadIdx.x;
    unsigned v = (gid < nt) ? a[gid] : 0;
    tmp[threadIdx.x] = v;
    __syncthreads();
    for (int off = 1; off < SCB; off <<= 1) {
        unsigned t = (threadIdx.x >= off) ? tmp[threadIdx.x - off] : 0;
        __syncthreads();
        tmp[threadIdx.x] += t;
        __syncthreads();
    }
    if (gid < nt) a[gid] = tmp[threadIdx.x] - v;   // exclusive
    if (threadIdx.x == SCB - 1) bs[blockIdx.x] = tmp[threadIdx.x];
}

__global__ __launch_bounds__(SCB) void scanT2_k(unsigned* __restrict__ bs, int nb) {
    __shared__ unsigned tmp[SCB];
    unsigned v = (threadIdx.x < nb) ? bs[threadIdx.x] : 0;
    tmp[threadIdx.x] = v;
    __syncthreads();
    for (int off = 1; off < SCB; off <<= 1) {
        unsigned t = (threadIdx.x >= off) ? tmp[threadIdx.x - off] : 0;
        __syncthreads();
        tmp[threadIdx.x] += t;
        __syncthreads();
    }
    if (threadIdx.x < nb) bs[threadIdx.x] = tmp[threadIdx.x] - v;  // exclusive
}

__global__ __launch_bounds__(SCB) void scanT3_k(unsigned* __restrict__ a,
                                                const unsigned* __restrict__ bs,
                                                int nt) {
    int gid = blockIdx.x * SCB + threadIdx.x;
    if (gid < nt) a[gid] += bs[gid / SCB];
}

// ---------------------------------------------------------------------------
// K3 (scatter2): same block<->edge mapping as hist. Places
//   srecI: (i&255)<<17 | j   at bucket-region cursor for i>>8
//   srecJ: (j&255)<<17 | i   at bucket-region cursor for j>>8
// via LDS cursors. No global atomics.
// ---------------------------------------------------------------------------
__global__ __launch_bounds__(256) void scatter2_k(
        const void* __restrict__ eidx, const int* __restrict__ flag,
        const unsigned* __restrict__ tabI, const unsigned* __restrict__ tabJ,
        unsigned* __restrict__ srecI, unsigned* __restrict__ srecJ,
        long long E, int nblkA, int NB) {
    __shared__ unsigned ci[512], cj[512];
    for (int b = threadIdx.x; b < NB; b += 256) {
        ci[b] = tabI[(size_t)b * nblkA + blockIdx.x];
        cj[b] = tabJ[(size_t)b * nblkA + blockIdx.x];
    }
    __syncthreads();
    int is64 = *flag;
    long long k0 = (long long)blockIdx.x * EPB;
    #pragma unroll 4
    for (int m = 0; m < EPB / 256; ++m) {
        long long k = k0 + m * 256 + threadIdx.x;
        if (k < E) {
            int j = load_idx(eidx, k, is64);
            int i = load_idx(eidx, E + k, is64);
            unsigned pI = atomicAdd(&ci[i >> 8], 1u);   // LDS atomic
            srecI[pI] = ((unsigned)(i & 255) << 17) | (unsigned)j;
            unsigned pJ = atomicAdd(&cj[j >> 8], 1u);   // LDS atomic
            srecJ[pJ] = ((unsigned)(j & 255) << 17) | (unsigned)i;
        }
    }
}

// ---------------------------------------------------------------------------
// K4 (finalizeJ): one workgroup per j-bucket. denom[j] = sum over the
// bucket's records of exp(leaky(ei[i]+ej[j])), accumulated in LDS (ds_add_f32
// on-CU atomics -- NOT the memory-side wall). ei reads are L2-resident (400KB).
// ---------------------------------------------------------------------------
__global__ __launch_bounds__(256) void finalizeJ_k(
        const unsigned* __restrict__ srecJ, const unsigned* __restrict__ tabJ,
        const float* __restrict__ ei_all, const float* __restrict__ ej_all,
        float* __restrict__ denom, int n, long long E, int nblkA, int NB) {
    int b = blockIdx.x;
    int tid = threadIdx.x;
    int base = (int)tabJ[(size_t)b * nblkA];
    int end  = (b + 1 < NB) ? (int)tabJ[(size_t)(b + 1) * nblkA] : (int)E;

    __shared__ float ejl[256];
    __shared__ float dsum[256];
    int g = b * 256 + tid;
    ejl[tid]  = (g < n) ? ej_all[g] : 0.f;
    dsum[tid] = 0.f;
    __syncthreads();

    for (int t = base + tid; t < end; t += 256) {
        unsigned r = srecJ[t];
        int jl = (int)(r >> 17);
        int i  = (int)(r & 0x1FFFFu);
        float e = ei_all[i] + ejl[jl];
        e = e > 0.f ? e : LEAKY * e;
        atomicAdd(&dsum[jl], __expf(e));          // LDS float atomic
    }
    __syncthreads();
    if (g < n) denom[g] = dsum[tid];
}

// ---------------------------------------------------------------------------
// K5 (finalizeI): one workgroup per i-bucket (256 nodes). LDS per-node counts
// + scan -> exact CSR start[]; recompute p, alpha = p/denom[j]; LDS-ranked
// slot; pje[slot] = j<<15 | round(alpha*32768).
// ---------------------------------------------------------------------------
__global__ __launch_bounds__(256) void finalizeI_k(
        const unsigned* __restrict__ srecI, const unsigned* __restrict__ tabI,
        const float* __restrict__ ei_all, const float* __restrict__ ej_all,
        const float* __restrict__ denom, int* __restrict__ start,
        unsigned* __restrict__ pje, int n, long long E, int nblkA, int NB) {
    int b = blockIdx.x;
    int tid = threadIdx.x;
    int base = (int)tabI[(size_t)b * nblkA];
    int end  = (b + 1 < NB) ? (int)tabI[(size_t)(b + 1) * nblkA] : (int)E;

    __shared__ int cnt[256];
    __shared__ int off[256];
    __shared__ float eil[256];
    int g = b * 256 + tid;
    cnt[tid] = 0;
    eil[tid] = (g < n) ? ei_all[g] : 0.f;
    __syncthreads();

    for (int t = base + tid; t < end; t += 256)
        atomicAdd(&cnt[srecI[t] >> 17], 1);
    __syncthreads();

    int v = cnt[tid];
    off[tid] = v;
    __syncthreads();
    for (int s = 1; s < 256; s <<= 1) {
        int t2 = (tid >= s) ? off[tid - s] : 0;
        __syncthreads();
        off[tid] += t2;
        __syncthreads();
    }
    int excl = off[tid] - v;
    if (g < n) start[g] = base + excl;
    if (b == NB - 1 && tid == 0) start[n] = (int)E;

    cnt[tid] = excl;   // reuse as cursor
    __syncthreads();

    for (int t = base + tid; t < end; t += 256) {
        unsigned r = srecI[t];
        int il = (int)(r >> 17);
        int j  = (int)(r & 0x1FFFFu);
        float e = eil[il] + ej_all[j];
        e = e > 0.f ? e : LEAKY * e;
        float alpha = __expf(e) / denom[j];
        unsigned aq = __float2uint_rn(alpha * 32768.f);
        if (aq > 32767u) aq = 32767u;
        int slot = base + atomicAdd(&cnt[il], 1);
        pje[slot] = ((unsigned)j << 15) | aq;
    }
}

// ---------------------------------------------------------------------------
// K6a: gather (bf16 rows): wave/node, 4B bf16x2 per lane, 2-deep pipeline on
// the packed (j,alpha) word, fused relu, single store.
// ---------------------------------------------------------------------------
__global__ __launch_bounds__(256) void gather_bf16_k(
        const int* __restrict__ start, const unsigned* __restrict__ pje,
        const ushort* __restrict__ xb, float* __restrict__ out, int n) {
    int wave = (int)((blockIdx.x * (long long)blockDim.x + threadIdx.x) >> 6);
    int lane = threadIdx.x & 63;
    if (wave >= n) return;
    int s = start[wave];
    int e_end = start[wave + 1];
    float ax = 0.f, ay = 0.f;
    unsigned ja = 0;
    if (s < e_end) ja = pje[s];
    for (int e = s; e < e_end; ++e) {
        unsigned cur = ja;
        if (e + 1 < e_end) ja = pje[e + 1];      // prefetch next pair
        float a = (float)(cur & 0x7FFFu) * (1.f / 32768.f);
        unsigned u = ((const unsigned*)(xb + (long long)(cur >> 15) * N_HID))[lane];
        float vx = __uint_as_float(u << 16);
        float vy = __uint_as_float(u & 0xffff0000u);
        ax += a * vx;
        ay += a * vy;
    }
    float2 r;
    r.x = fmaxf(ax, 0.f);
    r.y = fmaxf(ay, 0.f);
    ((float2*)(out + (long long)wave * N_HID))[lane] = r;
}

// K6b: fallback gather reading f32 x directly (if ws too small for xb).
__global__ __launch_bounds__(256) void gather_f32_k(
        const int* __restrict__ start, const unsigned* __restrict__ pje,
        const float* __restrict__ x, float* __restrict__ out, int n) {
    int wave = (int)((blockIdx.x * (long long)blockDim.x + threadIdx.x) >> 6);
    int lane = threadIdx.x & 63;
    if (wave >= n) return;
    int s = start[wave];
    int e_end = start[wave + 1];
    float ax = 0.f, ay = 0.f;
    unsigned ja = 0;
    if (s < e_end) ja = pje[s];
    for (int e = s; e < e_end; ++e) {
        unsigned cur = ja;
        if (e + 1 < e_end) ja = pje[e + 1];
        float a = (float)(cur & 0x7FFFu) * (1.f / 32768.f);
        float2 v = ((const float2*)(x + (long long)(cur >> 15) * N_HID))[lane];
        ax += a * v.x;
        ay += a * v.y;
    }
    float2 r;
    r.x = fmaxf(ax, 0.f);
    r.y = fmaxf(ay, 0.f);
    ((float2*)(out + (long long)wave * N_HID))[lane] = r;
}

extern "C" void kernel_launch(void* const* d_in, const int* in_sizes, int n_in,
                              void* d_out, int out_size, void* d_ws,
                              size_t ws_size, hipStream_t stream) {
    const float* x   = (const float*)d_in[0];
    const void*  eix = d_in[1];
    const float* w_i = (const float*)d_in[2];
    const float* w_j = (const float*)d_in[3];
    float* out = (float*)d_out;

    int n = in_sizes[0] / N_HID;            // 100000
    long long E = in_sizes[1] / 2;          // 1.6M

    int nblkA = (int)((E + EPB - 1) / EPB); // 391
    int NB    = (n + 255) / 256;            // 391 (<= 512 required)
    int NT    = NB * nblkA;                 // ~153k
    int nb1   = (NT + SCB - 1) / SCB;       // ~299 (<= 512 required)

    // ws layout (bytes), ~41.3 MB total:
    //   ei[n] ej[n] denom[n] f32 | start[n+1] int | tabI[NT] tabJ[NT] u32
    //   bs1[512] u32 | flag | srecI[E] u32 | pje[E] u32 (aliases srecJ)
    //   xb[n*128] u16 (optional)
    // srecJ aliases pje: srecJ is fully consumed by finalizeJ BEFORE
    // finalizeI writes pje.
    char* p = (char*)d_ws;
    float* ei_all = (float*)p;               p += (size_t)n * 4;
    float* ej_all = (float*)p;               p += (size_t)n * 4;
    float* denom  = (float*)p;               p += (size_t)n * 4;
    int*   start  = (int*)p;                 p += ((size_t)(n + 1) * 4 + 15) & ~15ull;
    unsigned* tabI = (unsigned*)p;           p += ((size_t)NT * 4 + 15) & ~15ull;
    unsigned* tabJ = (unsigned*)p;           p += ((size_t)NT * 4 + 15) & ~15ull;
    unsigned* bs1 = (unsigned*)p;            p += (size_t)SCB * 4;
    int*   flag   = (int*)p;                 p += 16;
    unsigned* srecI = (unsigned*)p;          p += (size_t)E * 4;
    unsigned* pje   = (unsigned*)p;          p += (size_t)E * 4;
    unsigned* srecJ = pje;                   // alias (see above)
    ushort* xb    = (ushort*)p;              p += (size_t)n * N_HID * 2;
    int wsBig = ((size_t)(p - (char*)d_ws) <= ws_size);
    if (!wsBig) xb = nullptr;

    detect_dtype_k<<<1, 256, 0, stream>>>(eix, E * 2, flag);

    long long t1 = (long long)n * 64;
    node_logits_k<<<(unsigned)((t1 + 255) / 256), 256, 0, stream>>>(
        x, w_i, w_j, ei_all, ej_all, xb, n);

    hist_k<<<nblkA, 256, 0, stream>>>(eix, flag, tabI, tabJ, E, nblkA, NB);

    scanT1_k<<<nb1, SCB, 0, stream>>>(tabI, bs1, NT);
    scanT2_k<<<1, SCB, 0, stream>>>(bs1, nb1);
    scanT3_k<<<nb1, SCB, 0, stream>>>(tabI, bs1, NT);
    scanT1_k<<<nb1, SCB, 0, stream>>>(tabJ, bs1, NT);
    scanT2_k<<<1, SCB, 0, stream>>>(bs1, nb1);
    scanT3_k<<<nb1, SCB, 0, stream>>>(tabJ, bs1, NT);

    scatter2_k<<<nblkA, 256, 0, stream>>>(eix, flag, tabI, tabJ, srecI, srecJ,
                                          E, nblkA, NB);

    finalizeJ_k<<<NB, 256, 0, stream>>>(srecJ, tabJ, ei_all, ej_all, denom,
                                        n, E, nblkA, NB);

    finalizeI_k<<<NB, 256, 0, stream>>>(srecI, tabI, ei_all, ej_all, denom,
                                        start, pje, n, E, nblkA, NB);

    long long t4 = (long long)n * 64;
    if (wsBig) {
        gather_bf16_k<<<(unsigned)((t4 + 255) / 256), 256, 0, stream>>>(
            start, pje, xb, out, n);
    } else {
        gather_f32_k<<<(unsigned)((t4 + 255) / 256), 256, 0, stream>>>(
            start, pje, x, out, n);
    }
}

// Round 9
// 205.889 us; speedup vs baseline: 1.6670x; 1.1608x over previous
//
#include <hip/hip_runtime.h>

#define N_HID 128
#define LEAKY 0.01f
#define EPB   4096      // edges per block in hist/scatter (256 thr x 16)
#define SCB   1024      // table-scan block size (2*NT elements, <=1024 blocks)

// ---------------------------------------------------------------------------
// helpers
// ---------------------------------------------------------------------------
__device__ inline ushort f2bf_rne(float f) {   // f32 -> bf16, round-nearest-even
    unsigned u = __float_as_uint(f);
    u += 0x7fffu + ((u >> 16) & 1u);
    return (ushort)(u >> 16);
}

__device__ inline int load_idx(const void* eidx, long long pos, int is64) {
    if (is64) return (int)((const long long*)eidx)[pos];
    return ((const int*)eidx)[pos];
}

// ---------------------------------------------------------------------------
// K0: detect int64 vs int32 edge_index.
// ---------------------------------------------------------------------------
__global__ void detect_dtype_k(const void* __restrict__ eidx, long long n_i64,
                               int* __restrict__ flag) {
    __shared__ int nonzero_hi;
    if (threadIdx.x == 0) nonzero_hi = 0;
    __syncthreads();
    const long long* p = (const long long*)eidx;
    long long samples = n_i64 < 4096 ? n_i64 : 4096;
    int bad = 0;
    for (long long k = threadIdx.x; k < samples; k += blockDim.x) {
        if ((p[k] >> 32) != 0) bad = 1;
    }
    if (bad) atomicOr(&nonzero_hi, 1);
    __syncthreads();
    if (threadIdx.x == 0) *flag = nonzero_hi ? 0 : 1;  // 1 => int64
}

// ---------------------------------------------------------------------------
// K1: per-node logits ei = x.w_i, ej = x.w_j (wave/node, shfl reduce).
// Fused: bf16-quantize the x row into xb.
// ---------------------------------------------------------------------------
__global__ __launch_bounds__(256) void node_logits_k(
        const float* __restrict__ x, const float* __restrict__ w_i,
        const float* __restrict__ w_j, float* __restrict__ ei_all,
        float* __restrict__ ej_all, ushort* __restrict__ xb, int n) {
    int wave = (int)((blockIdx.x * (long long)blockDim.x + threadIdx.x) >> 6);
    int lane = threadIdx.x & 63;
    if (wave >= n) return;
    const float2* xr = (const float2*)(x + (long long)wave * N_HID);
    float2 v  = xr[lane];
    float2 wi = ((const float2*)w_i)[lane];
    float2 wj = ((const float2*)w_j)[lane];
    if (xb) {
        unsigned packed = (unsigned)f2bf_rne(v.x) | ((unsigned)f2bf_rne(v.y) << 16);
        ((unsigned*)(xb + (long long)wave * N_HID))[lane] = packed;
    }
    float si = v.x * wi.x + v.y * wi.y;
    float sj = v.x * wj.x + v.y * wj.y;
    #pragma unroll
    for (int off = 32; off >= 1; off >>= 1) {
        si += __shfl_xor(si, off);
        sj += __shfl_xor(sj, off);
    }
    if (lane == 0) {
        ei_all[wave] = si;
        ej_all[wave] = sj;
    }
}

// ---------------------------------------------------------------------------
// K2 (hist): one pass over edges; LDS histograms of BOTH coarse buckets
// (i>>8 and j>>8). No global atomics.
// ---------------------------------------------------------------------------
__global__ __launch_bounds__(256) void hist_k(
        const void* __restrict__ eidx, const int* __restrict__ flag,
        unsigned* __restrict__ tabI, unsigned* __restrict__ tabJ,
        long long E, int nblkA, int NB) {
    __shared__ unsigned hi[512], hj[512];
    for (int b = threadIdx.x; b < NB; b += 256) { hi[b] = 0; hj[b] = 0; }
    __syncthreads();
    int is64 = *flag;
    long long k0 = (long long)blockIdx.x * EPB;
    #pragma unroll 4
    for (int m = 0; m < EPB / 256; ++m) {
        long long k = k0 + m * 256 + threadIdx.x;
        if (k < E) {
            int j = load_idx(eidx, k, is64);       // softmax group (source)
            int i = load_idx(eidx, E + k, is64);   // destination
            atomicAdd(&hi[i >> 8], 1u);            // LDS atomics only
            atomicAdd(&hj[j >> 8], 1u);
        }
    }
    __syncthreads();
    for (int b = threadIdx.x; b < NB; b += 256) {
        tabI[(size_t)b * nblkA + blockIdx.x] = hi[b];
        tabJ[(size_t)b * nblkA + blockIdx.x] = hj[b];
    }
}

// ---------------------------------------------------------------------------
// Exclusive scan over the CONCATENATED [tabI | tabJ] table (2*NT entries).
// tabJ entries come out biased by +E (total of tabI); consumers subtract E.
// nt2 = 2*NB*nblkA ~ 306k; nb1 = ceil(nt2/1024) ~ 299 <= 1024.
// ---------------------------------------------------------------------------
__global__ __launch_bounds__(SCB) void scanT1_k(unsigned* __restrict__ a,
                                                unsigned* __restrict__ bs, int nt) {
    __shared__ unsigned tmp[SCB];
    int gid = blockIdx.x * SCB + threadIdx.x;
    unsigned v = (gid < nt) ? a[gid] : 0;
    tmp[threadIdx.x] = v;
    __syncthreads();
    for (int off = 1; off < SCB; off <<= 1) {
        unsigned t = (threadIdx.x >= off) ? tmp[threadIdx.x - off] : 0;
        __syncthreads();
        tmp[threadIdx.x] += t;
        __syncthreads();
    }
    if (gid < nt) a[gid] = tmp[threadIdx.x] - v;   // exclusive
    if (threadIdx.x == SCB - 1) bs[blockIdx.x] = tmp[threadIdx.x];
}

__global__ __launch_bounds__(SCB) void scanT2_k(unsigned* __restrict__ bs, int nb) {
    __shared__ unsigned tmp[SCB];
    unsigned v = (threadIdx.x < nb) ? bs[threadIdx.x] : 0;
    tmp[threadIdx.x] = v;
    __syncthreads();
    for (int off = 1; off < SCB; off <<= 1) {
        unsigned t = (threadIdx.x >= off) ? tmp[threadIdx.x - off] : 0;
        __syncthreads();
        tmp[threadIdx.x] += t;
        __syncthreads();
    }
    if (threadIdx.x < nb) bs[threadIdx.x] = tmp[threadIdx.x] - v;  // exclusive
}

__global__ __launch_bounds__(SCB) void scanT3_k(unsigned* __restrict__ a,
                                                const unsigned* __restrict__ bs,
                                                int nt) {
    int gid = blockIdx.x * SCB + threadIdx.x;
    if (gid < nt) a[gid] += bs[gid / SCB];
}

// ---------------------------------------------------------------------------
// K3 (scatter2): same block<->edge mapping as hist. Places
//   srecI: (i&255)<<17 | j   at bucket-region cursor for i>>8
//   srecJ: (j&255)<<17 | i   at bucket-region cursor for j>>8
// via LDS cursors. No global atomics. tabJ entries carry +E bias.
// ---------------------------------------------------------------------------
__global__ __launch_bounds__(256) void scatter2_k(
        const void* __restrict__ eidx, const int* __restrict__ flag,
        const unsigned* __restrict__ tabI, const unsigned* __restrict__ tabJ,
        unsigned* __restrict__ srecI, unsigned* __restrict__ srecJ,
        long long E, int nblkA, int NB) {
    __shared__ unsigned ci[512], cj[512];
    unsigned Eu = (unsigned)E;
    for (int b = threadIdx.x; b < NB; b += 256) {
        ci[b] = tabI[(size_t)b * nblkA + blockIdx.x];
        cj[b] = tabJ[(size_t)b * nblkA + blockIdx.x] - Eu;   // unbias
    }
    __syncthreads();
    int is64 = *flag;
    long long k0 = (long long)blockIdx.x * EPB;
    #pragma unroll 4
    for (int m = 0; m < EPB / 256; ++m) {
        long long k = k0 + m * 256 + threadIdx.x;
        if (k < E) {
            int j = load_idx(eidx, k, is64);
            int i = load_idx(eidx, E + k, is64);
            unsigned pI = atomicAdd(&ci[i >> 8], 1u);   // LDS atomic
            srecI[pI] = ((unsigned)(i & 255) << 17) | (unsigned)j;
            unsigned pJ = atomicAdd(&cj[j >> 8], 1u);   // LDS atomic
            srecJ[pJ] = ((unsigned)(j & 255) << 17) | (unsigned)i;
        }
    }
}

// ---------------------------------------------------------------------------
// K4 (finalizeJ): one workgroup per j-bucket. denom[j] = sum over the
// bucket's records of exp(leaky(ei[i]+ej[j])), accumulated in LDS.
// ---------------------------------------------------------------------------
__global__ __launch_bounds__(256) void finalizeJ_k(
        const unsigned* __restrict__ srecJ, const unsigned* __restrict__ tabJ,
        const float* __restrict__ ei_all, const float* __restrict__ ej_all,
        float* __restrict__ denom, int n, long long E, int nblkA, int NB) {
    int b = blockIdx.x;
    int tid = threadIdx.x;
    unsigned Eu = (unsigned)E;
    int base = (int)(tabJ[(size_t)b * nblkA] - Eu);
    int end  = (b + 1 < NB) ? (int)(tabJ[(size_t)(b + 1) * nblkA] - Eu) : (int)E;

    __shared__ float ejl[256];
    __shared__ float dsum[256];
    int g = b * 256 + tid;
    ejl[tid]  = (g < n) ? ej_all[g] : 0.f;
    dsum[tid] = 0.f;
    __syncthreads();

    for (int t = base + tid; t < end; t += 256) {
        unsigned r = srecJ[t];
        int jl = (int)(r >> 17);
        int i  = (int)(r & 0x1FFFFu);
        float e = ei_all[i] + ejl[jl];
        e = e > 0.f ? e : LEAKY * e;
        atomicAdd(&dsum[jl], __expf(e));          // LDS float atomic
    }
    __syncthreads();
    if (g < n) denom[g] = dsum[tid];
}

// ---------------------------------------------------------------------------
// K5 (finalizeI): one workgroup per i-bucket (256 nodes). LDS per-node counts
// + scan -> exact CSR start[]; recompute p, alpha = p/denom[j]; LDS-ranked
// slot; pje[slot] = j<<15 | round(alpha*32768).
// ---------------------------------------------------------------------------
__global__ __launch_bounds__(256) void finalizeI_k(
        const unsigned* __restrict__ srecI, const unsigned* __restrict__ tabI,
        const float* __restrict__ ei_all, const float* __restrict__ ej_all,
        const float* __restrict__ denom, int* __restrict__ start,
        unsigned* __restrict__ pje, int n, long long E, int nblkA, int NB) {
    int b = blockIdx.x;
    int tid = threadIdx.x;
    int base = (int)tabI[(size_t)b * nblkA];
    int end  = (b + 1 < NB) ? (int)tabI[(size_t)(b + 1) * nblkA] : (int)E;

    __shared__ int cnt[256];
    __shared__ int off[256];
    __shared__ float eil[256];
    int g = b * 256 + tid;
    cnt[tid] = 0;
    eil[tid] = (g < n) ? ei_all[g] : 0.f;
    __syncthreads();

    for (int t = base + tid; t < end; t += 256)
        atomicAdd(&cnt[srecI[t] >> 17], 1);
    __syncthreads();

    int v = cnt[tid];
    off[tid] = v;
    __syncthreads();
    for (int s = 1; s < 256; s <<= 1) {
        int t2 = (tid >= s) ? off[tid - s] : 0;
        __syncthreads();
        off[tid] += t2;
        __syncthreads();
    }
    int excl = off[tid] - v;
    if (g < n) start[g] = base + excl;
    if (b == NB - 1 && tid == 0) start[n] = (int)E;

    cnt[tid] = excl;   // reuse as cursor
    __syncthreads();

    for (int t = base + tid; t < end; t += 256) {
        unsigned r = srecI[t];
        int il = (int)(r >> 17);
        int j  = (int)(r & 0x1FFFFu);
        float e = eil[il] + ej_all[j];
        e = e > 0.f ? e : LEAKY * e;
        float alpha = __expf(e) / denom[j];
        unsigned aq = __float2uint_rn(alpha * 32768.f);
        if (aq > 32767u) aq = 32767u;
        int slot = base + atomicAdd(&cnt[il], 1);
        pje[slot] = ((unsigned)j << 15) | aq;
    }
}

// ---------------------------------------------------------------------------
// K6a: quad-row gather (bf16): wave/node, 4 edges per loop iteration.
// 16 lanes per row x 16 B (uint4 = 8 bf16 cols). One vmem instruction fetches
// 4 independent random rows -> 4x memory-level parallelism per wave vs the
// old 1-row/iter structure. Tail slots decode to alpha=0 (harmless row 0).
// Fold sub-groups with shfl_xor(16|32); fused relu; float4 stores.
// ---------------------------------------------------------------------------
__global__ __launch_bounds__(256) void gather_bf16_k(
        const int* __restrict__ start, const unsigned* __restrict__ pje,
        const ushort* __restrict__ xb, float* __restrict__ out, int n) {
    int wave = (int)((blockIdx.x * (long long)blockDim.x + threadIdx.x) >> 6);
    int lane = threadIdx.x & 63;
    if (wave >= n) return;
    int s = start[wave];
    int e_end = start[wave + 1];
    int sub = lane >> 4;        // which edge of the quad (0..3)
    int col = lane & 15;        // 16B chunk within row (cols 8*col..8*col+7)

    float a0 = 0.f, a1 = 0.f, a2 = 0.f, a3 = 0.f;
    float a4 = 0.f, a5 = 0.f, a6 = 0.f, a7 = 0.f;
    for (int e = s; e < e_end; e += 4) {
        int ee = e + sub;
        unsigned cur = (ee < e_end) ? pje[ee] : 0u;   // 0 -> alpha=0, row 0
        float a = (float)(cur & 0x7FFFu) * (1.f / 32768.f);
        uint4 u = ((const uint4*)(xb + (size_t)(cur >> 15) * N_HID))[col];
        a0 += a * __uint_as_float(u.x << 16);
        a1 += a * __uint_as_float(u.x & 0xffff0000u);
        a2 += a * __uint_as_float(u.y << 16);
        a3 += a * __uint_as_float(u.y & 0xffff0000u);
        a4 += a * __uint_as_float(u.z << 16);
        a5 += a * __uint_as_float(u.z & 0xffff0000u);
        a6 += a * __uint_as_float(u.w << 16);
        a7 += a * __uint_as_float(u.w & 0xffff0000u);
    }
    // fold the 4 sub-groups (lanes differing in bits 4,5)
    a0 += __shfl_xor(a0, 16); a1 += __shfl_xor(a1, 16);
    a2 += __shfl_xor(a2, 16); a3 += __shfl_xor(a3, 16);
    a4 += __shfl_xor(a4, 16); a5 += __shfl_xor(a5, 16);
    a6 += __shfl_xor(a6, 16); a7 += __shfl_xor(a7, 16);
    a0 += __shfl_xor(a0, 32); a1 += __shfl_xor(a1, 32);
    a2 += __shfl_xor(a2, 32); a3 += __shfl_xor(a3, 32);
    a4 += __shfl_xor(a4, 32); a5 += __shfl_xor(a5, 32);
    a6 += __shfl_xor(a6, 32); a7 += __shfl_xor(a7, 32);

    float4* orow = (float4*)(out + (size_t)wave * N_HID);
    if (sub == 0) {
        float4 r;
        r.x = fmaxf(a0, 0.f); r.y = fmaxf(a1, 0.f);
        r.z = fmaxf(a2, 0.f); r.w = fmaxf(a3, 0.f);
        orow[col * 2] = r;
    } else if (sub == 1) {
        float4 r;
        r.x = fmaxf(a4, 0.f); r.y = fmaxf(a5, 0.f);
        r.z = fmaxf(a6, 0.f); r.w = fmaxf(a7, 0.f);
        orow[col * 2 + 1] = r;
    }
}

// K6b: fallback gather reading f32 x directly (if ws too small for xb).
__global__ __launch_bounds__(256) void gather_f32_k(
        const int* __restrict__ start, const unsigned* __restrict__ pje,
        const float* __restrict__ x, float* __restrict__ out, int n) {
    int wave = (int)((blockIdx.x * (long long)blockDim.x + threadIdx.x) >> 6);
    int lane = threadIdx.x & 63;
    if (wave >= n) return;
    int s = start[wave];
    int e_end = start[wave + 1];
    float ax = 0.f, ay = 0.f;
    unsigned ja = 0;
    if (s < e_end) ja = pje[s];
    for (int e = s; e < e_end; ++e) {
        unsigned cur = ja;
        if (e + 1 < e_end) ja = pje[e + 1];
        float a = (float)(cur & 0x7FFFu) * (1.f / 32768.f);
        float2 v = ((const float2*)(x + (long long)(cur >> 15) * N_HID))[lane];
        ax += a * v.x;
        ay += a * v.y;
    }
    float2 r;
    r.x = fmaxf(ax, 0.f);
    r.y = fmaxf(ay, 0.f);
    ((float2*)(out + (long long)wave * N_HID))[lane] = r;
}

extern "C" void kernel_launch(void* const* d_in, const int* in_sizes, int n_in,
                              void* d_out, int out_size, void* d_ws,
                              size_t ws_size, hipStream_t stream) {
    const float* x   = (const float*)d_in[0];
    const void*  eix = d_in[1];
    const float* w_i = (const float*)d_in[2];
    const float* w_j = (const float*)d_in[3];
    float* out = (float*)d_out;

    int n = in_sizes[0] / N_HID;            // 100000
    long long E = in_sizes[1] / 2;          // 1.6M

    int nblkA = (int)((E + EPB - 1) / EPB); // 391
    int NB    = (n + 255) / 256;            // 391 (<= 512 required)
    int NT    = NB * nblkA;                 // ~153k
    int NT2   = 2 * NT;                     // combined tabI|tabJ scan
    int nb1   = (NT2 + SCB - 1) / SCB;      // ~299 (<= 1024 required)

    // ws layout (bytes), ~41.3 MB total:
    //   ei[n] ej[n] denom[n] f32 | start[n+1] int | tab[2*NT] u32 (tabI|tabJ)
    //   bs1[SCB] u32 | flag | srecI[E] u32 | pje[E] u32 (aliases srecJ)
    //   xb[n*128] u16 (optional)
    // srecJ aliases pje: srecJ is fully consumed by finalizeJ BEFORE
    // finalizeI writes pje.
    char* p = (char*)d_ws;
    float* ei_all = (float*)p;               p += (size_t)n * 4;
    float* ej_all = (float*)p;               p += (size_t)n * 4;
    float* denom  = (float*)p;               p += (size_t)n * 4;
    int*   start  = (int*)p;                 p += ((size_t)(n + 1) * 4 + 15) & ~15ull;
    unsigned* tab = (unsigned*)p;            p += ((size_t)NT2 * 4 + 15) & ~15ull;
    unsigned* tabI = tab;
    unsigned* tabJ = tab + NT;               // contiguous for combined scan
    unsigned* bs1 = (unsigned*)p;            p += (size_t)SCB * 4;
    int*   flag   = (int*)p;                 p += 16;
    unsigned* srecI = (unsigned*)p;          p += (size_t)E * 4;
    unsigned* pje   = (unsigned*)p;          p += (size_t)E * 4;
    unsigned* srecJ = pje;                   // alias (see above)
    ushort* xb    = (ushort*)p;              p += (size_t)n * N_HID * 2;
    int wsBig = ((size_t)(p - (char*)d_ws) <= ws_size);
    if (!wsBig) xb = nullptr;

    detect_dtype_k<<<1, 256, 0, stream>>>(eix, E * 2, flag);

    long long t1 = (long long)n * 64;
    node_logits_k<<<(unsigned)((t1 + 255) / 256), 256, 0, stream>>>(
        x, w_i, w_j, ei_all, ej_all, xb, n);

    hist_k<<<nblkA, 256, 0, stream>>>(eix, flag, tabI, tabJ, E, nblkA, NB);

    scanT1_k<<<nb1, SCB, 0, stream>>>(tab, bs1, NT2);
    scanT2_k<<<1, SCB, 0, stream>>>(bs1, nb1);
    scanT3_k<<<nb1, SCB, 0, stream>>>(tab, bs1, NT2);

    scatter2_k<<<nblkA, 256, 0, stream>>>(eix, flag, tabI, tabJ, srecI, srecJ,
                                          E, nblkA, NB);

    finalizeJ_k<<<NB, 256, 0, stream>>>(srecJ, tabJ, ei_all, ej_all, denom,
                                        n, E, nblkA, NB);

    finalizeI_k<<<NB, 256, 0, stream>>>(srecI, tabI, ei_all, ej_all, denom,
                                        start, pje, n, E, nblkA, NB);

    long long t4 = (long long)n * 64;
    if (wsBig) {
        gather_bf16_k<<<(unsigned)((t4 + 255) / 256), 256, 0, stream>>>(
            start, pje, xb, out, n);
    } else {
        gather_f32_k<<<(unsigned)((t4 + 255) / 256), 256, 0, stream>>>(
            start, pje, x, out, n);
    }
}

// Round 10
// 202.860 us; speedup vs baseline: 1.6919x; 1.0149x over previous
//
#include <hip/hip_runtime.h>

#define N_HID 128
#define LEAKY 0.01f
#define EPB   4096      // edges per block in hist/scatter (256 thr x 16)
#define SCB   1024      // table-scan block size (2*NT elements, <=1024 blocks)

// ---------------------------------------------------------------------------
// helpers
// ---------------------------------------------------------------------------
__device__ inline ushort f2bf_rne(float f) {   // f32 -> bf16, round-nearest-even
    unsigned u = __float_as_uint(f);
    u += 0x7fffu + ((u >> 16) & 1u);
    return (ushort)(u >> 16);
}

__device__ inline int load_idx(const void* eidx, long long pos, int is64) {
    if (is64) return (int)((const long long*)eidx)[pos];
    return ((const int*)eidx)[pos];
}

// ---------------------------------------------------------------------------
// K0: detect int64 vs int32 edge_index.
// ---------------------------------------------------------------------------
__global__ void detect_dtype_k(const void* __restrict__ eidx, long long n_i64,
                               int* __restrict__ flag) {
    __shared__ int nonzero_hi;
    if (threadIdx.x == 0) nonzero_hi = 0;
    __syncthreads();
    const long long* p = (const long long*)eidx;
    long long samples = n_i64 < 4096 ? n_i64 : 4096;
    int bad = 0;
    for (long long k = threadIdx.x; k < samples; k += blockDim.x) {
        if ((p[k] >> 32) != 0) bad = 1;
    }
    if (bad) atomicOr(&nonzero_hi, 1);
    __syncthreads();
    if (threadIdx.x == 0) *flag = nonzero_hi ? 0 : 1;  // 1 => int64
}

// ---------------------------------------------------------------------------
// K1: per-node logits ei = x.w_i, ej = x.w_j (wave/node, shfl reduce).
// Fused: bf16-quantize the x row into xb.
// ---------------------------------------------------------------------------
__global__ __launch_bounds__(256) void node_logits_k(
        const float* __restrict__ x, const float* __restrict__ w_i,
        const float* __restrict__ w_j, float* __restrict__ ei_all,
        float* __restrict__ ej_all, ushort* __restrict__ xb, int n) {
    int wave = (int)((blockIdx.x * (long long)blockDim.x + threadIdx.x) >> 6);
    int lane = threadIdx.x & 63;
    if (wave >= n) return;
    const float2* xr = (const float2*)(x + (long long)wave * N_HID);
    float2 v  = xr[lane];
    float2 wi = ((const float2*)w_i)[lane];
    float2 wj = ((const float2*)w_j)[lane];
    if (xb) {
        unsigned packed = (unsigned)f2bf_rne(v.x) | ((unsigned)f2bf_rne(v.y) << 16);
        ((unsigned*)(xb + (long long)wave * N_HID))[lane] = packed;
    }
    float si = v.x * wi.x + v.y * wi.y;
    float sj = v.x * wj.x + v.y * wj.y;
    #pragma unroll
    for (int off = 32; off >= 1; off >>= 1) {
        si += __shfl_xor(si, off);
        sj += __shfl_xor(sj, off);
    }
    if (lane == 0) {
        ei_all[wave] = si;
        ej_all[wave] = sj;
    }
}

// ---------------------------------------------------------------------------
// K2 (hist): one pass over edges; LDS histograms of BOTH coarse buckets
// (i>>8 and j>>8). No global atomics.
// ---------------------------------------------------------------------------
__global__ __launch_bounds__(256) void hist_k(
        const void* __restrict__ eidx, const int* __restrict__ flag,
        unsigned* __restrict__ tabI, unsigned* __restrict__ tabJ,
        long long E, int nblkA, int NB) {
    __shared__ unsigned hi[512], hj[512];
    for (int b = threadIdx.x; b < NB; b += 256) { hi[b] = 0; hj[b] = 0; }
    __syncthreads();
    int is64 = *flag;
    long long k0 = (long long)blockIdx.x * EPB;
    #pragma unroll 4
    for (int m = 0; m < EPB / 256; ++m) {
        long long k = k0 + m * 256 + threadIdx.x;
        if (k < E) {
            int j = load_idx(eidx, k, is64);       // softmax group (source)
            int i = load_idx(eidx, E + k, is64);   // destination
            atomicAdd(&hi[i >> 8], 1u);            // LDS atomics only
            atomicAdd(&hj[j >> 8], 1u);
        }
    }
    __syncthreads();
    for (int b = threadIdx.x; b < NB; b += 256) {
        tabI[(size_t)b * nblkA + blockIdx.x] = hi[b];
        tabJ[(size_t)b * nblkA + blockIdx.x] = hj[b];
    }
}

// ---------------------------------------------------------------------------
// Exclusive scan over the CONCATENATED [tabI | tabJ] table (2*NT entries).
// tabJ entries come out biased by +E (total of tabI); consumers subtract E.
// ---------------------------------------------------------------------------
__global__ __launch_bounds__(SCB) void scanT1_k(unsigned* __restrict__ a,
                                                unsigned* __restrict__ bs, int nt) {
    __shared__ unsigned tmp[SCB];
    int gid = blockIdx.x * SCB + threadIdx.x;
    unsigned v = (gid < nt) ? a[gid] : 0;
    tmp[threadIdx.x] = v;
    __syncthreads();
    for (int off = 1; off < SCB; off <<= 1) {
        unsigned t = (threadIdx.x >= off) ? tmp[threadIdx.x - off] : 0;
        __syncthreads();
        tmp[threadIdx.x] += t;
        __syncthreads();
    }
    if (gid < nt) a[gid] = tmp[threadIdx.x] - v;   // exclusive
    if (threadIdx.x == SCB - 1) bs[blockIdx.x] = tmp[threadIdx.x];
}

__global__ __launch_bounds__(SCB) void scanT2_k(unsigned* __restrict__ bs, int nb) {
    __shared__ unsigned tmp[SCB];
    unsigned v = (threadIdx.x < nb) ? bs[threadIdx.x] : 0;
    tmp[threadIdx.x] = v;
    __syncthreads();
    for (int off = 1; off < SCB; off <<= 1) {
        unsigned t = (threadIdx.x >= off) ? tmp[threadIdx.x - off] : 0;
        __syncthreads();
        tmp[threadIdx.x] += t;
        __syncthreads();
    }
    if (threadIdx.x < nb) bs[threadIdx.x] = tmp[threadIdx.x] - v;  // exclusive
}

__global__ __launch_bounds__(SCB) void scanT3_k(unsigned* __restrict__ a,
                                                const unsigned* __restrict__ bs,
                                                int nt) {
    int gid = blockIdx.x * SCB + threadIdx.x;
    if (gid < nt) a[gid] += bs[gid / SCB];
}

// ---------------------------------------------------------------------------
// K3 (scatter2): same block<->edge mapping as hist. Places
//   srecI: (i&255)<<17 | j   at bucket-region cursor for i>>8
//   srecJ: (j&255)<<17 | i   at bucket-region cursor for j>>8
// via LDS cursors. No global atomics. tabJ entries carry +E bias.
// ---------------------------------------------------------------------------
__global__ __launch_bounds__(256) void scatter2_k(
        const void* __restrict__ eidx, const int* __restrict__ flag,
        const unsigned* __restrict__ tabI, const unsigned* __restrict__ tabJ,
        unsigned* __restrict__ srecI, unsigned* __restrict__ srecJ,
        long long E, int nblkA, int NB) {
    __shared__ unsigned ci[512], cj[512];
    unsigned Eu = (unsigned)E;
    for (int b = threadIdx.x; b < NB; b += 256) {
        ci[b] = tabI[(size_t)b * nblkA + blockIdx.x];
        cj[b] = tabJ[(size_t)b * nblkA + blockIdx.x] - Eu;   // unbias
    }
    __syncthreads();
    int is64 = *flag;
    long long k0 = (long long)blockIdx.x * EPB;
    #pragma unroll 4
    for (int m = 0; m < EPB / 256; ++m) {
        long long k = k0 + m * 256 + threadIdx.x;
        if (k < E) {
            int j = load_idx(eidx, k, is64);
            int i = load_idx(eidx, E + k, is64);
            unsigned pI = atomicAdd(&ci[i >> 8], 1u);   // LDS atomic
            srecI[pI] = ((unsigned)(i & 255) << 17) | (unsigned)j;
            unsigned pJ = atomicAdd(&cj[j >> 8], 1u);   // LDS atomic
            srecJ[pJ] = ((unsigned)(j & 255) << 17) | (unsigned)i;
        }
    }
}

// ---------------------------------------------------------------------------
// K4 (finalizeJ): one workgroup per j-bucket. denom[j] = sum over the
// bucket's records of exp(leaky(ei[i]+ej[j])), accumulated in LDS.
// ---------------------------------------------------------------------------
__global__ __launch_bounds__(256) void finalizeJ_k(
        const unsigned* __restrict__ srecJ, const unsigned* __restrict__ tabJ,
        const float* __restrict__ ei_all, const float* __restrict__ ej_all,
        float* __restrict__ denom, int n, long long E, int nblkA, int NB) {
    int b = blockIdx.x;
    int tid = threadIdx.x;
    unsigned Eu = (unsigned)E;
    int base = (int)(tabJ[(size_t)b * nblkA] - Eu);
    int end  = (b + 1 < NB) ? (int)(tabJ[(size_t)(b + 1) * nblkA] - Eu) : (int)E;

    __shared__ float ejl[256];
    __shared__ float dsum[256];
    int g = b * 256 + tid;
    ejl[tid]  = (g < n) ? ej_all[g] : 0.f;
    dsum[tid] = 0.f;
    __syncthreads();

    for (int t = base + tid; t < end; t += 256) {
        unsigned r = srecJ[t];
        int jl = (int)(r >> 17);
        int i  = (int)(r & 0x1FFFFu);
        float e = ei_all[i] + ejl[jl];
        e = e > 0.f ? e : LEAKY * e;
        atomicAdd(&dsum[jl], __expf(e));          // LDS float atomic
    }
    __syncthreads();
    if (g < n) denom[g] = dsum[tid];
}

// ---------------------------------------------------------------------------
// K5 (finalizeI): one workgroup per i-bucket (256 nodes). LDS per-node counts
// + scan -> exact CSR start[]; recompute p, alpha = p/denom[j]; LDS-ranked
// slot; pje[slot] = j<<15 | round(alpha*32768).
// ---------------------------------------------------------------------------
__global__ __launch_bounds__(256) void finalizeI_k(
        const unsigned* __restrict__ srecI, const unsigned* __restrict__ tabI,
        const float* __restrict__ ei_all, const float* __restrict__ ej_all,
        const float* __restrict__ denom, int* __restrict__ start,
        unsigned* __restrict__ pje, int n, long long E, int nblkA, int NB) {
    int b = blockIdx.x;
    int tid = threadIdx.x;
    int base = (int)tabI[(size_t)b * nblkA];
    int end  = (b + 1 < NB) ? (int)tabI[(size_t)(b + 1) * nblkA] : (int)E;

    __shared__ int cnt[256];
    __shared__ int off[256];
    __shared__ float eil[256];
    int g = b * 256 + tid;
    cnt[tid] = 0;
    eil[tid] = (g < n) ? ei_all[g] : 0.f;
    __syncthreads();

    for (int t = base + tid; t < end; t += 256)
        atomicAdd(&cnt[srecI[t] >> 17], 1);
    __syncthreads();

    int v = cnt[tid];
    off[tid] = v;
    __syncthreads();
    for (int s = 1; s < 256; s <<= 1) {
        int t2 = (tid >= s) ? off[tid - s] : 0;
        __syncthreads();
        off[tid] += t2;
        __syncthreads();
    }
    int excl = off[tid] - v;
    if (g < n) start[g] = base + excl;
    if (b == NB - 1 && tid == 0) start[n] = (int)E;

    cnt[tid] = excl;   // reuse as cursor
    __syncthreads();

    for (int t = base + tid; t < end; t += 256) {
        unsigned r = srecI[t];
        int il = (int)(r >> 17);
        int j  = (int)(r & 0x1FFFFu);
        float e = eil[il] + ej_all[j];
        e = e > 0.f ? e : LEAKY * e;
        float alpha = __expf(e) / denom[j];
        unsigned aq = __float2uint_rn(alpha * 32768.f);
        if (aq > 32767u) aq = 32767u;
        int slot = base + atomicAdd(&cnt[il], 1);
        pje[slot] = ((unsigned)j << 15) | aq;
    }
}

// ---------------------------------------------------------------------------
// K6a: oct-row gather (bf16): wave/node, 8 edges per loop iteration via TWO
// independent quad-loads (16 lanes x 16 B each) -> 2 row-loads in flight per
// wave, doubling MLP vs the quad version. Tail slots decode to alpha=0,
// row 0 (L1-hot, harmless). Fold sub-groups with shfl_xor(16|32); fused relu.
// ---------------------------------------------------------------------------
__global__ __launch_bounds__(256) void gather_bf16_k(
        const int* __restrict__ start, const unsigned* __restrict__ pje,
        const ushort* __restrict__ xb, float* __restrict__ out, int n) {
    int wave = (int)((blockIdx.x * (long long)blockDim.x + threadIdx.x) >> 6);
    int lane = threadIdx.x & 63;
    if (wave >= n) return;
    int s = start[wave];
    int e_end = start[wave + 1];
    int sub = lane >> 4;        // which edge of the quad (0..3)
    int col = lane & 15;        // 16B chunk within row (cols 8*col..8*col+7)

    float a0 = 0.f, a1 = 0.f, a2 = 0.f, a3 = 0.f;
    float a4 = 0.f, a5 = 0.f, a6 = 0.f, a7 = 0.f;
    for (int e = s; e < e_end; e += 8) {
        int ee0 = e + sub;
        int ee1 = e + 4 + sub;
        unsigned cur0 = (ee0 < e_end) ? pje[ee0] : 0u;   // 0 -> alpha=0, row 0
        unsigned cur1 = (ee1 < e_end) ? pje[ee1] : 0u;
        float af0 = (float)(cur0 & 0x7FFFu) * (1.f / 32768.f);
        float af1 = (float)(cur1 & 0x7FFFu) * (1.f / 32768.f);
        uint4 u0 = ((const uint4*)(xb + (size_t)(cur0 >> 15) * N_HID))[col];
        uint4 u1 = ((const uint4*)(xb + (size_t)(cur1 >> 15) * N_HID))[col];
        a0 += af0 * __uint_as_float(u0.x << 16);
        a1 += af0 * __uint_as_float(u0.x & 0xffff0000u);
        a2 += af0 * __uint_as_float(u0.y << 16);
        a3 += af0 * __uint_as_float(u0.y & 0xffff0000u);
        a4 += af0 * __uint_as_float(u0.z << 16);
        a5 += af0 * __uint_as_float(u0.z & 0xffff0000u);
        a6 += af0 * __uint_as_float(u0.w << 16);
        a7 += af0 * __uint_as_float(u0.w & 0xffff0000u);
        a0 += af1 * __uint_as_float(u1.x << 16);
        a1 += af1 * __uint_as_float(u1.x & 0xffff0000u);
        a2 += af1 * __uint_as_float(u1.y << 16);
        a3 += af1 * __uint_as_float(u1.y & 0xffff0000u);
        a4 += af1 * __uint_as_float(u1.z << 16);
        a5 += af1 * __uint_as_float(u1.z & 0xffff0000u);
        a6 += af1 * __uint_as_float(u1.w << 16);
        a7 += af1 * __uint_as_float(u1.w & 0xffff0000u);
    }
    // fold the 4 sub-groups (lanes differing in bits 4,5)
    a0 += __shfl_xor(a0, 16); a1 += __shfl_xor(a1, 16);
    a2 += __shfl_xor(a2, 16); a3 += __shfl_xor(a3, 16);
    a4 += __shfl_xor(a4, 16); a5 += __shfl_xor(a5, 16);
    a6 += __shfl_xor(a6, 16); a7 += __shfl_xor(a7, 16);
    a0 += __shfl_xor(a0, 32); a1 += __shfl_xor(a1, 32);
    a2 += __shfl_xor(a2, 32); a3 += __shfl_xor(a3, 32);
    a4 += __shfl_xor(a4, 32); a5 += __shfl_xor(a5, 32);
    a6 += __shfl_xor(a6, 32); a7 += __shfl_xor(a7, 32);

    float4* orow = (float4*)(out + (size_t)wave * N_HID);
    if (sub == 0) {
        float4 r;
        r.x = fmaxf(a0, 0.f); r.y = fmaxf(a1, 0.f);
        r.z = fmaxf(a2, 0.f); r.w = fmaxf(a3, 0.f);
        orow[col * 2] = r;
    } else if (sub == 1) {
        float4 r;
        r.x = fmaxf(a4, 0.f); r.y = fmaxf(a5, 0.f);
        r.z = fmaxf(a6, 0.f); r.w = fmaxf(a7, 0.f);
        orow[col * 2 + 1] = r;
    }
}

// K6b: fallback gather reading f32 x directly (if ws too small for xb).
__global__ __launch_bounds__(256) void gather_f32_k(
        const int* __restrict__ start, const unsigned* __restrict__ pje,
        const float* __restrict__ x, float* __restrict__ out, int n) {
    int wave = (int)((blockIdx.x * (long long)blockDim.x + threadIdx.x) >> 6);
    int lane = threadIdx.x & 63;
    if (wave >= n) return;
    int s = start[wave];
    int e_end = start[wave + 1];
    float ax = 0.f, ay = 0.f;
    unsigned ja = 0;
    if (s < e_end) ja = pje[s];
    for (int e = s; e < e_end; ++e) {
        unsigned cur = ja;
        if (e + 1 < e_end) ja = pje[e + 1];
        float a = (float)(cur & 0x7FFFu) * (1.f / 32768.f);
        float2 v = ((const float2*)(x + (long long)(cur >> 15) * N_HID))[lane];
        ax += a * v.x;
        ay += a * v.y;
    }
    float2 r;
    r.x = fmaxf(ax, 0.f);
    r.y = fmaxf(ay, 0.f);
    ((float2*)(out + (long long)wave * N_HID))[lane] = r;
}

extern "C" void kernel_launch(void* const* d_in, const int* in_sizes, int n_in,
                              void* d_out, int out_size, void* d_ws,
                              size_t ws_size, hipStream_t stream) {
    const float* x   = (const float*)d_in[0];
    const void*  eix = d_in[1];
    const float* w_i = (const float*)d_in[2];
    const float* w_j = (const float*)d_in[3];
    float* out = (float*)d_out;

    int n = in_sizes[0] / N_HID;            // 100000
    long long E = in_sizes[1] / 2;          // 1.6M

    int nblkA = (int)((E + EPB - 1) / EPB); // 391
    int NB    = (n + 255) / 256;            // 391 (<= 512 required)
    int NT    = NB * nblkA;                 // ~153k
    int NT2   = 2 * NT;                     // combined tabI|tabJ scan
    int nb1   = (NT2 + SCB - 1) / SCB;      // ~299 (<= 1024 required)

    // ws layout (bytes), ~41.3 MB total:
    //   ei[n] ej[n] denom[n] f32 | start[n+1] int | tab[2*NT] u32 (tabI|tabJ)
    //   bs1[SCB] u32 | flag | srecI[E] u32 | pje[E] u32 (aliases srecJ)
    //   xb[n*128] u16 (optional)
    // srecJ aliases pje: srecJ is fully consumed by finalizeJ BEFORE
    // finalizeI writes pje.
    char* p = (char*)d_ws;
    float* ei_all = (float*)p;               p += (size_t)n * 4;
    float* ej_all = (float*)p;               p += (size_t)n * 4;
    float* denom  = (float*)p;               p += (size_t)n * 4;
    int*   start  = (int*)p;                 p += ((size_t)(n + 1) * 4 + 15) & ~15ull;
    unsigned* tab = (unsigned*)p;            p += ((size_t)NT2 * 4 + 15) & ~15ull;
    unsigned* tabI = tab;
    unsigned* tabJ = tab + NT;               // contiguous for combined scan
    unsigned* bs1 = (unsigned*)p;            p += (size_t)SCB * 4;
    int*   flag   = (int*)p;                 p += 16;
    unsigned* srecI = (unsigned*)p;          p += (size_t)E * 4;
    unsigned* pje   = (unsigned*)p;          p += (size_t)E * 4;
    unsigned* srecJ = pje;                   // alias (see above)
    ushort* xb    = (ushort*)p;              p += (size_t)n * N_HID * 2;
    int wsBig = ((size_t)(p - (char*)d_ws) <= ws_size);
    if (!wsBig) xb = nullptr;

    detect_dtype_k<<<1, 256, 0, stream>>>(eix, E * 2, flag);

    long long t1 = (long long)n * 64;
    node_logits_k<<<(unsigned)((t1 + 255) / 256), 256, 0, stream>>>(
        x, w_i, w_j, ei_all, ej_all, xb, n);

    hist_k<<<nblkA, 256, 0, stream>>>(eix, flag, tabI, tabJ, E, nblkA, NB);

    scanT1_k<<<nb1, SCB, 0, stream>>>(tab, bs1, NT2);
    scanT2_k<<<1, SCB, 0, stream>>>(bs1, nb1);
    scanT3_k<<<nb1, SCB, 0, stream>>>(tab, bs1, NT2);

    scatter2_k<<<nblkA, 256, 0, stream>>>(eix, flag, tabI, tabJ, srecI, srecJ,
                                          E, nblkA, NB);

    finalizeJ_k<<<NB, 256, 0, stream>>>(srecJ, tabJ, ei_all, ej_all, denom,
                                        n, E, nblkA, NB);

    finalizeI_k<<<NB, 256, 0, stream>>>(srecI, tabI, ei_all, ej_all, denom,
                                        start, pje, n, E, nblkA, NB);

    long long t4 = (long long)n * 64;
    if (wsBig) {
        gather_bf16_k<<<(unsigned)((t4 + 255) / 256), 256, 0, stream>>>(
            start, pje, xb, out, n);
    } else {
        gather_f32_k<<<(unsigned)((t4 + 255) / 256), 256, 0, stream>>>(
            start, pje, x, out, n);
    }
}

// Round 11
// 201.893 us; speedup vs baseline: 1.7000x; 1.0048x over previous
//
#include <hip/hip_runtime.h>

#define N_HID 128
#define LEAKY 0.01f
#define EPB   2048      // edges per block in hist/scatter (256 thr x 8)
#define SCB   1024      // table-scan block size
#define TABV(g) (tab[g] + bs1[(g) >> 10])   // scan correction applied at read

// ---------------------------------------------------------------------------
// helpers
// ---------------------------------------------------------------------------
__device__ inline ushort f2bf_rne(float f) {   // f32 -> bf16, round-nearest-even
    unsigned u = __float_as_uint(f);
    u += 0x7fffu + ((u >> 16) & 1u);
    return (ushort)(u >> 16);
}

__device__ inline int load_idx(const void* eidx, long long pos, int is64) {
    if (is64) return (int)((const long long*)eidx)[pos];
    return ((const int*)eidx)[pos];
}

// ---------------------------------------------------------------------------
// K0: detect int64 vs int32 edge_index.
// ---------------------------------------------------------------------------
__global__ void detect_dtype_k(const void* __restrict__ eidx, long long n_i64,
                               int* __restrict__ flag) {
    __shared__ int nonzero_hi;
    if (threadIdx.x == 0) nonzero_hi = 0;
    __syncthreads();
    const long long* p = (const long long*)eidx;
    long long samples = n_i64 < 4096 ? n_i64 : 4096;
    int bad = 0;
    for (long long k = threadIdx.x; k < samples; k += blockDim.x) {
        if ((p[k] >> 32) != 0) bad = 1;
    }
    if (bad) atomicOr(&nonzero_hi, 1);
    __syncthreads();
    if (threadIdx.x == 0) *flag = nonzero_hi ? 0 : 1;  // 1 => int64
}

// ---------------------------------------------------------------------------
// K1: per-node logits ei = x.w_i, ej = x.w_j (wave/node, shfl reduce).
// Fused: bf16-quantize the x row into xb.
// ---------------------------------------------------------------------------
__global__ __launch_bounds__(256) void node_logits_k(
        const float* __restrict__ x, const float* __restrict__ w_i,
        const float* __restrict__ w_j, float* __restrict__ ei_all,
        float* __restrict__ ej_all, ushort* __restrict__ xb, int n) {
    int wave = (int)((blockIdx.x * (long long)blockDim.x + threadIdx.x) >> 6);
    int lane = threadIdx.x & 63;
    if (wave >= n) return;
    const float2* xr = (const float2*)(x + (long long)wave * N_HID);
    float2 v  = xr[lane];
    float2 wi = ((const float2*)w_i)[lane];
    float2 wj = ((const float2*)w_j)[lane];
    if (xb) {
        unsigned packed = (unsigned)f2bf_rne(v.x) | ((unsigned)f2bf_rne(v.y) << 16);
        ((unsigned*)(xb + (long long)wave * N_HID))[lane] = packed;
    }
    float si = v.x * wi.x + v.y * wi.y;
    float sj = v.x * wj.x + v.y * wj.y;
    #pragma unroll
    for (int off = 32; off >= 1; off >>= 1) {
        si += __shfl_xor(si, off);
        sj += __shfl_xor(sj, off);
    }
    if (lane == 0) {
        ei_all[wave] = si;
        ej_all[wave] = sj;
    }
}

// ---------------------------------------------------------------------------
// K2 (hist): one pass over edges; LDS histograms of BOTH coarse buckets
// (i>>8 and j>>8). No global atomics. 782 blocks for occupancy.
// ---------------------------------------------------------------------------
__global__ __launch_bounds__(256) void hist_k(
        const void* __restrict__ eidx, const int* __restrict__ flag,
        unsigned* __restrict__ tabI, unsigned* __restrict__ tabJ,
        long long E, int nblkA, int NB) {
    __shared__ unsigned hi[512], hj[512];
    for (int b = threadIdx.x; b < NB; b += 256) { hi[b] = 0; hj[b] = 0; }
    __syncthreads();
    int is64 = *flag;
    long long k0 = (long long)blockIdx.x * EPB;
    #pragma unroll 4
    for (int m = 0; m < EPB / 256; ++m) {
        long long k = k0 + m * 256 + threadIdx.x;
        if (k < E) {
            int j = load_idx(eidx, k, is64);       // softmax group (source)
            int i = load_idx(eidx, E + k, is64);   // destination
            atomicAdd(&hi[i >> 8], 1u);            // LDS atomics only
            atomicAdd(&hj[j >> 8], 1u);
        }
    }
    __syncthreads();
    for (int b = threadIdx.x; b < NB; b += 256) {
        tabI[(size_t)b * nblkA + blockIdx.x] = hi[b];
        tabJ[(size_t)b * nblkA + blockIdx.x] = hj[b];
    }
}

// ---------------------------------------------------------------------------
// 2-level exclusive scan over the CONCATENATED [tabI | tabJ] table.
// Block-offset correction (bs1) is applied lazily at read time via TABV.
// tabJ entries carry +E bias (total of tabI); consumers subtract E.
// ---------------------------------------------------------------------------
__global__ __launch_bounds__(SCB) void scanT1_k(unsigned* __restrict__ a,
                                                unsigned* __restrict__ bs, int nt) {
    __shared__ unsigned tmp[SCB];
    int gid = blockIdx.x * SCB + threadIdx.x;
    unsigned v = (gid < nt) ? a[gid] : 0;
    tmp[threadIdx.x] = v;
    __syncthreads();
    for (int off = 1; off < SCB; off <<= 1) {
        unsigned t = (threadIdx.x >= off) ? tmp[threadIdx.x - off] : 0;
        __syncthreads();
        tmp[threadIdx.x] += t;
        __syncthreads();
    }
    if (gid < nt) a[gid] = tmp[threadIdx.x] - v;   // exclusive within block
    if (threadIdx.x == SCB - 1) bs[blockIdx.x] = tmp[threadIdx.x];
}

__global__ __launch_bounds__(SCB) void scanT2_k(unsigned* __restrict__ bs, int nb) {
    __shared__ unsigned tmp[SCB];
    unsigned v = (threadIdx.x < nb) ? bs[threadIdx.x] : 0;
    tmp[threadIdx.x] = v;
    __syncthreads();
    for (int off = 1; off < SCB; off <<= 1) {
        unsigned t = (threadIdx.x >= off) ? tmp[threadIdx.x - off] : 0;
        __syncthreads();
        tmp[threadIdx.x] += t;
        __syncthreads();
    }
    if (threadIdx.x < nb) bs[threadIdx.x] = tmp[threadIdx.x] - v;  // exclusive
}

// ---------------------------------------------------------------------------
// K3 (scatter2): same block<->edge mapping as hist. Places
//   srecI: (i&255)<<17 | j   at bucket-region cursor for i>>8
//   srecJ: (j&255)<<17 | i   at bucket-region cursor for j>>8
// via LDS cursors. No global atomics.
// ---------------------------------------------------------------------------
__global__ __launch_bounds__(256) void scatter2_k(
        const void* __restrict__ eidx, const int* __restrict__ flag,
        const unsigned* __restrict__ tab, const unsigned* __restrict__ bs1,
        unsigned* __restrict__ srecI, unsigned* __restrict__ srecJ,
        long long E, int nblkA, int NB, int NT) {
    __shared__ unsigned ci[512], cj[512];
    unsigned Eu = (unsigned)E;
    for (int b = threadIdx.x; b < NB; b += 256) {
        size_t gI = (size_t)b * nblkA + blockIdx.x;
        size_t gJ = (size_t)NT + gI;
        ci[b] = TABV(gI);
        cj[b] = TABV(gJ) - Eu;   // unbias
    }
    __syncthreads();
    int is64 = *flag;
    long long k0 = (long long)blockIdx.x * EPB;
    #pragma unroll 4
    for (int m = 0; m < EPB / 256; ++m) {
        long long k = k0 + m * 256 + threadIdx.x;
        if (k < E) {
            int j = load_idx(eidx, k, is64);
            int i = load_idx(eidx, E + k, is64);
            unsigned pI = atomicAdd(&ci[i >> 8], 1u);   // LDS atomic
            srecI[pI] = ((unsigned)(i & 255) << 17) | (unsigned)j;
            unsigned pJ = atomicAdd(&cj[j >> 8], 1u);   // LDS atomic
            srecJ[pJ] = ((unsigned)(j & 255) << 17) | (unsigned)i;
        }
    }
}

// ---------------------------------------------------------------------------
// K4 (finalizeJ): one 512-thread workgroup per j-bucket. denom[j] = sum of
// exp(leaky(ei[i]+ej[j])) over the bucket's records, accumulated in LDS.
// Writes packed (ej, denom) float2 for finalizeI.
// ---------------------------------------------------------------------------
__global__ __launch_bounds__(512) void finalizeJ_k(
        const unsigned* __restrict__ srecJ, const unsigned* __restrict__ tab,
        const unsigned* __restrict__ bs1, const float* __restrict__ ei_all,
        const float* __restrict__ ej_all, float2* __restrict__ ejd,
        int n, long long E, int nblkA, int NB, int NT) {
    int b = blockIdx.x;
    int tid = threadIdx.x;
    unsigned Eu = (unsigned)E;
    size_t gJ0 = (size_t)NT + (size_t)b * nblkA;
    int base = (int)(TABV(gJ0) - Eu);
    int end  = (b + 1 < NB) ? (int)(TABV(gJ0 + nblkA) - Eu) : (int)E;

    __shared__ float ejl[256];
    __shared__ float dsum[256];
    int g = b * 256 + tid;
    if (tid < 256) {
        ejl[tid]  = (g < n) ? ej_all[g] : 0.f;
        dsum[tid] = 0.f;
    }
    __syncthreads();

    for (int t = base + tid; t < end; t += 512) {
        unsigned r = srecJ[t];
        int jl = (int)(r >> 17);
        int i  = (int)(r & 0x1FFFFu);
        float e = ei_all[i] + ejl[jl];
        e = e > 0.f ? e : LEAKY * e;
        atomicAdd(&dsum[jl], __expf(e));          // LDS float atomic
    }
    __syncthreads();
    if (tid < 256 && g < n) {
        float2 r2;
        r2.x = ejl[tid];
        r2.y = dsum[tid];
        ejd[g] = r2;
    }
}

// ---------------------------------------------------------------------------
// K5 (finalizeI): one 512-thread workgroup per i-bucket (256 nodes). LDS
// per-node counts + scan -> exact CSR start[]; alpha = exp(leaky)/denom via
// one float2 gather; LDS-ranked slot; pje[slot] = j<<15 | round(alpha*32768).
// ---------------------------------------------------------------------------
__global__ __launch_bounds__(512) void finalizeI_k(
        const unsigned* __restrict__ srecI, const unsigned* __restrict__ tab,
        const unsigned* __restrict__ bs1, const float* __restrict__ ei_all,
        const float2* __restrict__ ejd, int* __restrict__ start,
        unsigned* __restrict__ pje, int n, long long E, int nblkA, int NB,
        int NT) {
    int b = blockIdx.x;
    int tid = threadIdx.x;
    size_t gI0 = (size_t)b * nblkA;
    int base = (int)TABV(gI0);
    int end  = (b + 1 < NB) ? (int)TABV(gI0 + nblkA) : (int)E;

    __shared__ int cnt[256];
    __shared__ int off[256];
    __shared__ float eil[256];
    int g = b * 256 + tid;
    if (tid < 256) {
        cnt[tid] = 0;
        eil[tid] = (g < n) ? ei_all[g] : 0.f;
    }
    __syncthreads();

    for (int t = base + tid; t < end; t += 512)
        atomicAdd(&cnt[srecI[t] >> 17], 1);
    __syncthreads();

    // exclusive scan of cnt[256] (threads >=256 only hit the barriers)
    int v = 0;
    if (tid < 256) { v = cnt[tid]; off[tid] = v; }
    __syncthreads();
    for (int s = 1; s < 256; s <<= 1) {
        int t2 = 0;
        if (tid < 256 && tid >= s) t2 = off[tid - s];
        __syncthreads();
        if (tid < 256) off[tid] += t2;
        __syncthreads();
    }
    if (tid < 256) {
        int excl = off[tid] - v;
        if (g < n) start[g] = base + excl;
        cnt[tid] = excl;   // reuse as cursor
    }
    if (b == NB - 1 && tid == 0) start[n] = (int)E;
    __syncthreads();

    for (int t = base + tid; t < end; t += 512) {
        unsigned r = srecI[t];
        int il = (int)(r >> 17);
        int j  = (int)(r & 0x1FFFFu);
        float2 ed = ejd[j];                       // (ej, denom) in one load
        float e = eil[il] + ed.x;
        e = e > 0.f ? e : LEAKY * e;
        float alpha = __expf(e) / ed.y;
        unsigned aq = __float2uint_rn(alpha * 32768.f);
        if (aq > 32767u) aq = 32767u;
        int slot = base + atomicAdd(&cnt[il], 1);
        pje[slot] = ((unsigned)j << 15) | aq;
    }
}

// ---------------------------------------------------------------------------
// K6a: oct-row gather (bf16): wave/node, 8 edges per loop iteration via TWO
// independent quad-loads (16 lanes x 16 B each). Tail slots decode to
// alpha=0, row 0 (L1-hot, harmless). Fold sub-groups with shfl_xor(16|32).
// ---------------------------------------------------------------------------
__global__ __launch_bounds__(256) void gather_bf16_k(
        const int* __restrict__ start, const unsigned* __restrict__ pje,
        const ushort* __restrict__ xb, float* __restrict__ out, int n) {
    int wave = (int)((blockIdx.x * (long long)blockDim.x + threadIdx.x) >> 6);
    int lane = threadIdx.x & 63;
    if (wave >= n) return;
    int s = start[wave];
    int e_end = start[wave + 1];
    int sub = lane >> 4;        // which edge of the quad (0..3)
    int col = lane & 15;        // 16B chunk within row (cols 8*col..8*col+7)

    float a0 = 0.f, a1 = 0.f, a2 = 0.f, a3 = 0.f;
    float a4 = 0.f, a5 = 0.f, a6 = 0.f, a7 = 0.f;
    for (int e = s; e < e_end; e += 8) {
        int ee0 = e + sub;
        int ee1 = e + 4 + sub;
        unsigned cur0 = (ee0 < e_end) ? pje[ee0] : 0u;   // 0 -> alpha=0, row 0
        unsigned cur1 = (ee1 < e_end) ? pje[ee1] : 0u;
        float af0 = (float)(cur0 & 0x7FFFu) * (1.f / 32768.f);
        float af1 = (float)(cur1 & 0x7FFFu) * (1.f / 32768.f);
        uint4 u0 = ((const uint4*)(xb + (size_t)(cur0 >> 15) * N_HID))[col];
        uint4 u1 = ((const uint4*)(xb + (size_t)(cur1 >> 15) * N_HID))[col];
        a0 += af0 * __uint_as_float(u0.x << 16);
        a1 += af0 * __uint_as_float(u0.x & 0xffff0000u);
        a2 += af0 * __uint_as_float(u0.y << 16);
        a3 += af0 * __uint_as_float(u0.y & 0xffff0000u);
        a4 += af0 * __uint_as_float(u0.z << 16);
        a5 += af0 * __uint_as_float(u0.z & 0xffff0000u);
        a6 += af0 * __uint_as_float(u0.w << 16);
        a7 += af0 * __uint_as_float(u0.w & 0xffff0000u);
        a0 += af1 * __uint_as_float(u1.x << 16);
        a1 += af1 * __uint_as_float(u1.x & 0xffff0000u);
        a2 += af1 * __uint_as_float(u1.y << 16);
        a3 += af1 * __uint_as_float(u1.y & 0xffff0000u);
        a4 += af1 * __uint_as_float(u1.z << 16);
        a5 += af1 * __uint_as_float(u1.z & 0xffff0000u);
        a6 += af1 * __uint_as_float(u1.w << 16);
        a7 += af1 * __uint_as_float(u1.w & 0xffff0000u);
    }
    // fold the 4 sub-groups (lanes differing in bits 4,5)
    a0 += __shfl_xor(a0, 16); a1 += __shfl_xor(a1, 16);
    a2 += __shfl_xor(a2, 16); a3 += __shfl_xor(a3, 16);
    a4 += __shfl_xor(a4, 16); a5 += __shfl_xor(a5, 16);
    a6 += __shfl_xor(a6, 16); a7 += __shfl_xor(a7, 16);
    a0 += __shfl_xor(a0, 32); a1 += __shfl_xor(a1, 32);
    a2 += __shfl_xor(a2, 32); a3 += __shfl_xor(a3, 32);
    a4 += __shfl_xor(a4, 32); a5 += __shfl_xor(a5, 32);
    a6 += __shfl_xor(a6, 32); a7 += __shfl_xor(a7, 32);

    float4* orow = (float4*)(out + (size_t)wave * N_HID);
    if (sub == 0) {
        float4 r;
        r.x = fmaxf(a0, 0.f); r.y = fmaxf(a1, 0.f);
        r.z = fmaxf(a2, 0.f); r.w = fmaxf(a3, 0.f);
        orow[col * 2] = r;
    } else if (sub == 1) {
        float4 r;
        r.x = fmaxf(a4, 0.f); r.y = fmaxf(a5, 0.f);
        r.z = fmaxf(a6, 0.f); r.w = fmaxf(a7, 0.f);
        orow[col * 2 + 1] = r;
    }
}

// K6b: fallback gather reading f32 x directly (if ws too small for xb).
__global__ __launch_bounds__(256) void gather_f32_k(
        const int* __restrict__ start, const unsigned* __restrict__ pje,
        const float* __restrict__ x, float* __restrict__ out, int n) {
    int wave = (int)((blockIdx.x * (long long)blockDim.x + threadIdx.x) >> 6);
    int lane = threadIdx.x & 63;
    if (wave >= n) return;
    int s = start[wave];
    int e_end = start[wave + 1];
    float ax = 0.f, ay = 0.f;
    unsigned ja = 0;
    if (s < e_end) ja = pje[s];
    for (int e = s; e < e_end; ++e) {
        unsigned cur = ja;
        if (e + 1 < e_end) ja = pje[e + 1];
        float a = (float)(cur & 0x7FFFu) * (1.f / 32768.f);
        float2 v = ((const float2*)(x + (long long)(cur >> 15) * N_HID))[lane];
        ax += a * v.x;
        ay += a * v.y;
    }
    float2 r;
    r.x = fmaxf(ax, 0.f);
    r.y = fmaxf(ay, 0.f);
    ((float2*)(out + (long long)wave * N_HID))[lane] = r;
}

extern "C" void kernel_launch(void* const* d_in, const int* in_sizes, int n_in,
                              void* d_out, int out_size, void* d_ws,
                              size_t ws_size, hipStream_t stream) {
    const float* x   = (const float*)d_in[0];
    const void*  eix = d_in[1];
    const float* w_i = (const float*)d_in[2];
    const float* w_j = (const float*)d_in[3];
    float* out = (float*)d_out;

    int n = in_sizes[0] / N_HID;            // 100000
    long long E = in_sizes[1] / 2;          // 1.6M

    int nblkA = (int)((E + EPB - 1) / EPB); // 782
    int NB    = (n + 255) / 256;            // 391 (<= 512 required)
    int NT    = NB * nblkA;                 // ~306k
    int NT2   = 2 * NT;                     // combined tabI|tabJ scan ~611k
    int nb1   = (NT2 + SCB - 1) / SCB;      // ~598 (<= 1024 required)

    // ws layout (bytes), ~42.9 MB total:
    //   ei[n] ej[n] f32 | ejd[n] float2 | start[n+1] int | tab[2*NT] u32
    //   bs1[SCB] u32 | flag | srecI[E] u32 | pje[E] u32 (aliases srecJ)
    //   xb[n*128] u16 (optional)
    // srecJ aliases pje: srecJ is fully consumed by finalizeJ BEFORE
    // finalizeI writes pje.
    char* p = (char*)d_ws;
    float* ei_all = (float*)p;               p += (size_t)n * 4;
    float* ej_all = (float*)p;               p += (size_t)n * 4;
    float2* ejd   = (float2*)p;              p += (size_t)n * 8;
    int*   start  = (int*)p;                 p += ((size_t)(n + 1) * 4 + 15) & ~15ull;
    unsigned* tab = (unsigned*)p;            p += ((size_t)NT2 * 4 + 15) & ~15ull;
    unsigned* tabI = tab;
    unsigned* tabJ = tab + NT;               // contiguous for combined scan
    unsigned* bs1 = (unsigned*)p;            p += (size_t)SCB * 4;
    int*   flag   = (int*)p;                 p += 16;
    unsigned* srecI = (unsigned*)p;          p += (size_t)E * 4;
    unsigned* pje   = (unsigned*)p;          p += (size_t)E * 4;
    unsigned* srecJ = pje;                   // alias (see above)
    ushort* xb    = (ushort*)p;              p += (size_t)n * N_HID * 2;
    int wsBig = ((size_t)(p - (char*)d_ws) <= ws_size);
    if (!wsBig) xb = nullptr;

    detect_dtype_k<<<1, 256, 0, stream>>>(eix, E * 2, flag);

    long long t1 = (long long)n * 64;
    node_logits_k<<<(unsigned)((t1 + 255) / 256), 256, 0, stream>>>(
        x, w_i, w_j, ei_all, ej_all, xb, n);

    hist_k<<<nblkA, 256, 0, stream>>>(eix, flag, tabI, tabJ, E, nblkA, NB);

    scanT1_k<<<nb1, SCB, 0, stream>>>(tab, bs1, NT2);
    scanT2_k<<<1, SCB, 0, stream>>>(bs1, nb1);

    scatter2_k<<<nblkA, 256, 0, stream>>>(eix, flag, tab, bs1, srecI, srecJ,
                                          E, nblkA, NB, NT);

    finalizeJ_k<<<NB, 512, 0, stream>>>(srecJ, tab, bs1, ei_all, ej_all, ejd,
                                        n, E, nblkA, NB, NT);

    finalizeI_k<<<NB, 512, 0, stream>>>(srecI, tab, bs1, ei_all, ejd,
                                        start, pje, n, E, nblkA, NB, NT);

    long long t4 = (long long)n * 64;
    if (wsBig) {
        gather_bf16_k<<<(unsigned)((t4 + 255) / 256), 256, 0, stream>>>(
            start, pje, xb, out, n);
    } else {
        gather_f32_k<<<(unsigned)((t4 + 255) / 256), 256, 0, stream>>>(
            start, pje, x, out, n);
    }
}

// Round 12
// 188.807 us; speedup vs baseline: 1.8178x; 1.0693x over previous
//
#include <hip/hip_runtime.h>

#define N_HID 128
#define LEAKY 0.01f
#define EPB   2048      // edges per block in hist/scatter (256 thr x 8)
#define SCB   1024      // table-scan block size
#define TABV(g) (tab[g] + bs1[(g) >> 10])   // scan correction applied at read

// ---------------------------------------------------------------------------
// helpers
// ---------------------------------------------------------------------------
__device__ inline ushort f2bf_rne(float f) {   // f32 -> bf16, round-nearest-even
    unsigned u = __float_as_uint(f);
    u += 0x7fffu + ((u >> 16) & 1u);
    return (ushort)(u >> 16);
}

__device__ inline int load_idx(const void* eidx, long long pos, int is64) {
    if (is64) return (int)((const long long*)eidx)[pos];
    return ((const int*)eidx)[pos];
}

// Wave-uniform int64-vs-int32 detection: lanes ballot on the high words of
// the first 64 int64-interpreted entries. int32 data -> high words are later
// random indices (nonzero w.p. ~1); int64 indices (<2^31) -> all zero.
__device__ inline int detect64(const void* eidx, int lane) {
    const long long* p = (const long long*)eidx;
    unsigned long long b = __ballot((p[lane] >> 32) != 0);
    return b == 0ull;
}

// ---------------------------------------------------------------------------
// K1 (fused): blocks [0, nblkA): LDS histogram of both coarse buckets
// (i>>8, j>>8) -> tabI/tabJ. blocks [nblkA, nblkA+nblkL): per-node logits
// ei = x.w_i, ej = x.w_j (wave/node, shfl reduce) + bf16-quantize x into xb.
// Independent inputs -> safely concurrent in one dispatch.
// ---------------------------------------------------------------------------
__global__ __launch_bounds__(256) void logits_hist_k(
        const float* __restrict__ x, const float* __restrict__ w_i,
        const float* __restrict__ w_j, float* __restrict__ ei_all,
        float* __restrict__ ej_all, ushort* __restrict__ xb,
        const void* __restrict__ eidx, unsigned* __restrict__ tabI,
        unsigned* __restrict__ tabJ, int n, long long E,
        int nblkA, int NB) {
    __shared__ unsigned hi[512], hj[512];
    int lane = threadIdx.x & 63;
    if (blockIdx.x < (unsigned)nblkA) {
        // ---- hist part ----
        for (int b = threadIdx.x; b < NB; b += 256) { hi[b] = 0; hj[b] = 0; }
        __syncthreads();
        int is64 = detect64(eidx, lane);
        long long k0 = (long long)blockIdx.x * EPB;
        #pragma unroll 4
        for (int m = 0; m < EPB / 256; ++m) {
            long long k = k0 + m * 256 + threadIdx.x;
            if (k < E) {
                int j = load_idx(eidx, k, is64);       // softmax group (src)
                int i = load_idx(eidx, E + k, is64);   // destination
                atomicAdd(&hi[i >> 8], 1u);            // LDS atomics only
                atomicAdd(&hj[j >> 8], 1u);
            }
        }
        __syncthreads();
        for (int b = threadIdx.x; b < NB; b += 256) {
            tabI[(size_t)b * nblkA + blockIdx.x] = hi[b];
            tabJ[(size_t)b * nblkA + blockIdx.x] = hj[b];
        }
    } else {
        // ---- logits part ----
        int blk = blockIdx.x - nblkA;
        int wave = blk * 4 + (int)(threadIdx.x >> 6);
        if (wave >= n) return;
        const float2* xr = (const float2*)(x + (long long)wave * N_HID);
        float2 v  = xr[lane];
        float2 wi = ((const float2*)w_i)[lane];
        float2 wj = ((const float2*)w_j)[lane];
        if (xb) {
            unsigned pk = (unsigned)f2bf_rne(v.x) | ((unsigned)f2bf_rne(v.y) << 16);
            ((unsigned*)(xb + (long long)wave * N_HID))[lane] = pk;
        }
        float si = v.x * wi.x + v.y * wi.y;
        float sj = v.x * wj.x + v.y * wj.y;
        #pragma unroll
        for (int off = 32; off >= 1; off >>= 1) {
            si += __shfl_xor(si, off);
            sj += __shfl_xor(sj, off);
        }
        if (lane == 0) {
            ei_all[wave] = si;
            ej_all[wave] = sj;
        }
    }
}

// ---------------------------------------------------------------------------
// 2-level exclusive scan over the CONCATENATED [tabI | tabJ] table.
// Block-offset correction (bs1) applied lazily at read time via TABV.
// tabJ entries carry +E bias (total of tabI); consumers subtract E.
// ---------------------------------------------------------------------------
__global__ __launch_bounds__(SCB) void scanT1_k(unsigned* __restrict__ a,
                                                unsigned* __restrict__ bs, int nt) {
    __shared__ unsigned tmp[SCB];
    int gid = blockIdx.x * SCB + threadIdx.x;
    unsigned v = (gid < nt) ? a[gid] : 0;
    tmp[threadIdx.x] = v;
    __syncthreads();
    for (int off = 1; off < SCB; off <<= 1) {
        unsigned t = (threadIdx.x >= off) ? tmp[threadIdx.x - off] : 0;
        __syncthreads();
        tmp[threadIdx.x] += t;
        __syncthreads();
    }
    if (gid < nt) a[gid] = tmp[threadIdx.x] - v;   // exclusive within block
    if (threadIdx.x == SCB - 1) bs[blockIdx.x] = tmp[threadIdx.x];
}

__global__ __launch_bounds__(SCB) void scanT2_k(unsigned* __restrict__ bs, int nb) {
    __shared__ unsigned tmp[SCB];
    unsigned v = (threadIdx.x < nb) ? bs[threadIdx.x] : 0;
    tmp[threadIdx.x] = v;
    __syncthreads();
    for (int off = 1; off < SCB; off <<= 1) {
        unsigned t = (threadIdx.x >= off) ? tmp[threadIdx.x - off] : 0;
        __syncthreads();
        tmp[threadIdx.x] += t;
        __syncthreads();
    }
    if (threadIdx.x < nb) bs[threadIdx.x] = tmp[threadIdx.x] - v;  // exclusive
}

// ---------------------------------------------------------------------------
// K3 (scatter2): same block<->edge mapping as hist. Places
//   srecI: (i&255)<<17 | j   at bucket-region cursor for i>>8
//   srecJ: (j&255)<<17 | i   at bucket-region cursor for j>>8
// via LDS cursors. No global atomics.
// ---------------------------------------------------------------------------
__global__ __launch_bounds__(256) void scatter2_k(
        const void* __restrict__ eidx, const unsigned* __restrict__ tab,
        const unsigned* __restrict__ bs1, unsigned* __restrict__ srecI,
        unsigned* __restrict__ srecJ, long long E, int nblkA, int NB, int NT) {
    __shared__ unsigned ci[512], cj[512];
    unsigned Eu = (unsigned)E;
    for (int b = threadIdx.x; b < NB; b += 256) {
        size_t gI = (size_t)b * nblkA + blockIdx.x;
        size_t gJ = (size_t)NT + gI;
        ci[b] = TABV(gI);
        cj[b] = TABV(gJ) - Eu;   // unbias
    }
    __syncthreads();
    int is64 = detect64(eidx, threadIdx.x & 63);
    long long k0 = (long long)blockIdx.x * EPB;
    #pragma unroll 4
    for (int m = 0; m < EPB / 256; ++m) {
        long long k = k0 + m * 256 + threadIdx.x;
        if (k < E) {
            int j = load_idx(eidx, k, is64);
            int i = load_idx(eidx, E + k, is64);
            unsigned pI = atomicAdd(&ci[i >> 8], 1u);   // LDS atomic
            srecI[pI] = ((unsigned)(i & 255) << 17) | (unsigned)j;
            unsigned pJ = atomicAdd(&cj[j >> 8], 1u);   // LDS atomic
            srecJ[pJ] = ((unsigned)(j & 255) << 17) | (unsigned)i;
        }
    }
}

// ---------------------------------------------------------------------------
// K4 (finalizeJ): one 512-thread workgroup per j-bucket. denom[j] = sum of
// exp(leaky(ei[i]+ej[j])) over the bucket's records, accumulated in LDS.
// Writes packed (ej, denom) float2 for finalizeI.
// ---------------------------------------------------------------------------
__global__ __launch_bounds__(512) void finalizeJ_k(
        const unsigned* __restrict__ srecJ, const unsigned* __restrict__ tab,
        const unsigned* __restrict__ bs1, const float* __restrict__ ei_all,
        const float* __restrict__ ej_all, float2* __restrict__ ejd,
        int n, long long E, int nblkA, int NB, int NT) {
    int b = blockIdx.x;
    int tid = threadIdx.x;
    unsigned Eu = (unsigned)E;
    size_t gJ0 = (size_t)NT + (size_t)b * nblkA;
    int base = (int)(TABV(gJ0) - Eu);
    int end  = (b + 1 < NB) ? (int)(TABV(gJ0 + nblkA) - Eu) : (int)E;

    __shared__ float ejl[256];
    __shared__ float dsum[256];
    int g = b * 256 + tid;
    if (tid < 256) {
        ejl[tid]  = (g < n) ? ej_all[g] : 0.f;
        dsum[tid] = 0.f;
    }
    __syncthreads();

    for (int t = base + tid; t < end; t += 512) {
        unsigned r = srecJ[t];
        int jl = (int)(r >> 17);
        int i  = (int)(r & 0x1FFFFu);
        float e = ei_all[i] + ejl[jl];
        e = e > 0.f ? e : LEAKY * e;
        atomicAdd(&dsum[jl], __expf(e));          // LDS float atomic
    }
    __syncthreads();
    if (tid < 256 && g < n) {
        float2 r2;
        r2.x = ejl[tid];
        r2.y = dsum[tid];
        ejd[g] = r2;
    }
}

// ---------------------------------------------------------------------------
// K5 (finalizeI): one 512-thread workgroup per i-bucket (256 nodes). LDS
// per-node counts + scan -> exact CSR start[]; alpha = exp(leaky)/denom via
// one float2 gather; LDS-ranked slot; pje[slot] = j<<15 | round(alpha*32768).
// ---------------------------------------------------------------------------
__global__ __launch_bounds__(512) void finalizeI_k(
        const unsigned* __restrict__ srecI, const unsigned* __restrict__ tab,
        const unsigned* __restrict__ bs1, const float* __restrict__ ei_all,
        const float2* __restrict__ ejd, int* __restrict__ start,
        unsigned* __restrict__ pje, int n, long long E, int nblkA, int NB,
        int NT) {
    int b = blockIdx.x;
    int tid = threadIdx.x;
    size_t gI0 = (size_t)b * nblkA;
    int base = (int)TABV(gI0);
    int end  = (b + 1 < NB) ? (int)TABV(gI0 + nblkA) : (int)E;

    __shared__ int cnt[256];
    __shared__ int off[256];
    __shared__ float eil[256];
    int g = b * 256 + tid;
    if (tid < 256) {
        cnt[tid] = 0;
        eil[tid] = (g < n) ? ei_all[g] : 0.f;
    }
    __syncthreads();

    for (int t = base + tid; t < end; t += 512)
        atomicAdd(&cnt[srecI[t] >> 17], 1);
    __syncthreads();

    // exclusive scan of cnt[256] (threads >=256 only hit the barriers)
    int v = 0;
    if (tid < 256) { v = cnt[tid]; off[tid] = v; }
    __syncthreads();
    for (int s = 1; s < 256; s <<= 1) {
        int t2 = 0;
        if (tid < 256 && tid >= s) t2 = off[tid - s];
        __syncthreads();
        if (tid < 256) off[tid] += t2;
        __syncthreads();
    }
    if (tid < 256) {
        int excl = off[tid] - v;
        if (g < n) start[g] = base + excl;
        cnt[tid] = excl;   // reuse as cursor
    }
    if (b == NB - 1 && tid == 0) start[n] = (int)E;
    __syncthreads();

    for (int t = base + tid; t < end; t += 512) {
        unsigned r = srecI[t];
        int il = (int)(r >> 17);
        int j  = (int)(r & 0x1FFFFu);
        float2 ed = ejd[j];                       // (ej, denom) in one load
        float e = eil[il] + ed.x;
        e = e > 0.f ? e : LEAKY * e;
        float alpha = __expf(e) / ed.y;
        unsigned aq = __float2uint_rn(alpha * 32768.f);
        if (aq > 32767u) aq = 32767u;
        int slot = base + atomicAdd(&cnt[il], 1);
        pje[slot] = ((unsigned)j << 15) | aq;
    }
}

// ---------------------------------------------------------------------------
// K6a: oct-row gather (bf16) with software-pipelined pje loads: the two pje
// words for iteration k+1 are issued during iteration k's row-FMAs, hiding
// the pje->row dependent-chain latency. 8 edges/iter via two independent
// quad-loads (16 lanes x 16 B). Tail slots decode to alpha=0, row 0.
// ---------------------------------------------------------------------------
__global__ __launch_bounds__(256) void gather_bf16_k(
        const int* __restrict__ start, const unsigned* __restrict__ pje,
        const ushort* __restrict__ xb, float* __restrict__ out, int n) {
    int wave = (int)((blockIdx.x * (long long)blockDim.x + threadIdx.x) >> 6);
    int lane = threadIdx.x & 63;
    if (wave >= n) return;
    int s = start[wave];
    int e_end = start[wave + 1];
    int sub = lane >> 4;        // which edge of the quad (0..3)
    int col = lane & 15;        // 16B chunk within row (cols 8*col..8*col+7)

    float a0 = 0.f, a1 = 0.f, a2 = 0.f, a3 = 0.f;
    float a4 = 0.f, a5 = 0.f, a6 = 0.f, a7 = 0.f;
    int p0 = s + sub, p1 = s + 4 + sub;
    unsigned nc0 = (p0 < e_end) ? pje[p0] : 0u;
    unsigned nc1 = (p1 < e_end) ? pje[p1] : 0u;
    for (int e = s; e < e_end; e += 8) {
        unsigned cur0 = nc0, cur1 = nc1;
        int q0 = e + 8 + sub, q1 = e + 12 + sub;
        nc0 = (q0 < e_end) ? pje[q0] : 0u;        // prefetch next iter
        nc1 = (q1 < e_end) ? pje[q1] : 0u;
        float af0 = (float)(cur0 & 0x7FFFu) * (1.f / 32768.f);
        float af1 = (float)(cur1 & 0x7FFFu) * (1.f / 32768.f);
        uint4 u0 = ((const uint4*)(xb + (size_t)(cur0 >> 15) * N_HID))[col];
        uint4 u1 = ((const uint4*)(xb + (size_t)(cur1 >> 15) * N_HID))[col];
        a0 += af0 * __uint_as_float(u0.x << 16);
        a1 += af0 * __uint_as_float(u0.x & 0xffff0000u);
        a2 += af0 * __uint_as_float(u0.y << 16);
        a3 += af0 * __uint_as_float(u0.y & 0xffff0000u);
        a4 += af0 * __uint_as_float(u0.z << 16);
        a5 += af0 * __uint_as_float(u0.z & 0xffff0000u);
        a6 += af0 * __uint_as_float(u0.w << 16);
        a7 += af0 * __uint_as_float(u0.w & 0xffff0000u);
        a0 += af1 * __uint_as_float(u1.x << 16);
        a1 += af1 * __uint_as_float(u1.x & 0xffff0000u);
        a2 += af1 * __uint_as_float(u1.y << 16);
        a3 += af1 * __uint_as_float(u1.y & 0xffff0000u);
        a4 += af1 * __uint_as_float(u1.z << 16);
        a5 += af1 * __uint_as_float(u1.z & 0xffff0000u);
        a6 += af1 * __uint_as_float(u1.w << 16);
        a7 += af1 * __uint_as_float(u1.w & 0xffff0000u);
    }
    // fold the 4 sub-groups (lanes differing in bits 4,5)
    a0 += __shfl_xor(a0, 16); a1 += __shfl_xor(a1, 16);
    a2 += __shfl_xor(a2, 16); a3 += __shfl_xor(a3, 16);
    a4 += __shfl_xor(a4, 16); a5 += __shfl_xor(a5, 16);
    a6 += __shfl_xor(a6, 16); a7 += __shfl_xor(a7, 16);
    a0 += __shfl_xor(a0, 32); a1 += __shfl_xor(a1, 32);
    a2 += __shfl_xor(a2, 32); a3 += __shfl_xor(a3, 32);
    a4 += __shfl_xor(a4, 32); a5 += __shfl_xor(a5, 32);
    a6 += __shfl_xor(a6, 32); a7 += __shfl_xor(a7, 32);

    float4* orow = (float4*)(out + (size_t)wave * N_HID);
    if (sub == 0) {
        float4 r;
        r.x = fmaxf(a0, 0.f); r.y = fmaxf(a1, 0.f);
        r.z = fmaxf(a2, 0.f); r.w = fmaxf(a3, 0.f);
        orow[col * 2] = r;
    } else if (sub == 1) {
        float4 r;
        r.x = fmaxf(a4, 0.f); r.y = fmaxf(a5, 0.f);
        r.z = fmaxf(a6, 0.f); r.w = fmaxf(a7, 0.f);
        orow[col * 2 + 1] = r;
    }
}

// K6b: fallback gather reading f32 x directly (if ws too small for xb).
__global__ __launch_bounds__(256) void gather_f32_k(
        const int* __restrict__ start, const unsigned* __restrict__ pje,
        const float* __restrict__ x, float* __restrict__ out, int n) {
    int wave = (int)((blockIdx.x * (long long)blockDim.x + threadIdx.x) >> 6);
    int lane = threadIdx.x & 63;
    if (wave >= n) return;
    int s = start[wave];
    int e_end = start[wave + 1];
    float ax = 0.f, ay = 0.f;
    unsigned ja = 0;
    if (s < e_end) ja = pje[s];
    for (int e = s; e < e_end; ++e) {
        unsigned cur = ja;
        if (e + 1 < e_end) ja = pje[e + 1];
        float a = (float)(cur & 0x7FFFu) * (1.f / 32768.f);
        float2 v = ((const float2*)(x + (long long)(cur >> 15) * N_HID))[lane];
        ax += a * v.x;
        ay += a * v.y;
    }
    float2 r;
    r.x = fmaxf(ax, 0.f);
    r.y = fmaxf(ay, 0.f);
    ((float2*)(out + (long long)wave * N_HID))[lane] = r;
}

extern "C" void kernel_launch(void* const* d_in, const int* in_sizes, int n_in,
                              void* d_out, int out_size, void* d_ws,
                              size_t ws_size, hipStream_t stream) {
    const float* x   = (const float*)d_in[0];
    const void*  eix = d_in[1];
    const float* w_i = (const float*)d_in[2];
    const float* w_j = (const float*)d_in[3];
    float* out = (float*)d_out;

    int n = in_sizes[0] / N_HID;            // 100000
    long long E = in_sizes[1] / 2;          // 1.6M

    int nblkA = (int)((E + EPB - 1) / EPB); // 782
    int nblkL = (n + 3) / 4;                // logits blocks (4 nodes/block)
    int NB    = (n + 255) / 256;            // 391 (<= 512 required)
    int NT    = NB * nblkA;                 // ~306k
    int NT2   = 2 * NT;                     // combined tabI|tabJ scan ~611k
    int nb1   = (NT2 + SCB - 1) / SCB;      // ~598 (<= 1024 required)

    // ws layout (bytes), ~42.9 MB total:
    //   ei[n] ej[n] f32 | ejd[n] float2 | start[n+1] int | tab[2*NT] u32
    //   bs1[SCB] u32 | srecI[E] u32 | pje[E] u32 (aliases srecJ)
    //   xb[n*128] u16 (optional)
    // srecJ aliases pje: srecJ is fully consumed by finalizeJ BEFORE
    // finalizeI writes pje.
    char* p = (char*)d_ws;
    float* ei_all = (float*)p;               p += (size_t)n * 4;
    float* ej_all = (float*)p;               p += (size_t)n * 4;
    float2* ejd   = (float2*)p;              p += (size_t)n * 8;
    int*   start  = (int*)p;                 p += ((size_t)(n + 1) * 4 + 15) & ~15ull;
    unsigned* tab = (unsigned*)p;            p += ((size_t)NT2 * 4 + 15) & ~15ull;
    unsigned* tabI = tab;
    unsigned* tabJ = tab + NT;               // contiguous for combined scan
    unsigned* bs1 = (unsigned*)p;            p += (size_t)SCB * 4;
    unsigned* srecI = (unsigned*)p;          p += (size_t)E * 4;
    unsigned* pje   = (unsigned*)p;          p += (size_t)E * 4;
    unsigned* srecJ = pje;                   // alias (see above)
    ushort* xb    = (ushort*)p;              p += (size_t)n * N_HID * 2;
    int wsBig = ((size_t)(p - (char*)d_ws) <= ws_size);
    if (!wsBig) xb = nullptr;

    logits_hist_k<<<(unsigned)(nblkA + nblkL), 256, 0, stream>>>(
        x, w_i, w_j, ei_all, ej_all, xb, eix, tabI, tabJ, n, E, nblkA, NB);

    scanT1_k<<<nb1, SCB, 0, stream>>>(tab, bs1, NT2);
    scanT2_k<<<1, SCB, 0, stream>>>(bs1, nb1);

    scatter2_k<<<nblkA, 256, 0, stream>>>(eix, tab, bs1, srecI, srecJ,
                                          E, nblkA, NB, NT);

    finalizeJ_k<<<NB, 512, 0, stream>>>(srecJ, tab, bs1, ei_all, ej_all, ejd,
                                        n, E, nblkA, NB, NT);

    finalizeI_k<<<NB, 512, 0, stream>>>(srecI, tab, bs1, ei_all, ejd,
                                        start, pje, n, E, nblkA, NB, NT);

    long long t4 = (long long)n * 64;
    if (wsBig) {
        gather_bf16_k<<<(unsigned)((t4 + 255) / 256), 256, 0, stream>>>(
            start, pje, xb, out, n);
    } else {
        gather_f32_k<<<(unsigned)((t4 + 255) / 256), 256, 0, stream>>>(
            start, pje, x, out, n);
    }
}

// Round 13
// 169.016 us; speedup vs baseline: 2.0306x; 1.1171x over previous
//
#include <hip/hip_runtime.h>

#define N_HID 128
#define LEAKY 0.01f
#define EPB   2048      // edges per block in hist/scatter (256 thr x 8)
#define SCB   1024      // table-scan block size
#define TABV(g) (tab[g] + bs1[(g) >> 10])   // scan correction applied at read

__device__ inline int load_idx(const void* eidx, long long pos, int is64) {
    if (is64) return (int)((const long long*)eidx)[pos];
    return ((const int*)eidx)[pos];
}

// Wave-uniform int64-vs-int32 detection: lanes ballot on the high words of
// the first 64 int64-interpreted entries. int32 data -> high words are later
// random indices (nonzero w.p. ~1); int64 indices (<2^31) -> all zero.
__device__ inline int detect64(const void* eidx, int lane) {
    const long long* p = (const long long*)eidx;
    unsigned long long b = __ballot((p[lane] >> 32) != 0);
    return b == 0ull;
}

// ---------------------------------------------------------------------------
// K1 (fused): blocks [0, nblkA): LDS histogram of both coarse buckets
// (i>>8, j>>8) -> tabI/tabJ. blocks [nblkA, ...): per-node logits
// ei = x.w_i, ej = x.w_j (wave/node, shfl butterfly) + int8-quantize the row
// (per-row scale) into xq/xs. Independent inputs -> concurrent in 1 dispatch.
// ---------------------------------------------------------------------------
__global__ __launch_bounds__(256) void logits_hist_k(
        const float* __restrict__ x, const float* __restrict__ w_i,
        const float* __restrict__ w_j, float* __restrict__ ei_all,
        float* __restrict__ ej_all, signed char* __restrict__ xq,
        float* __restrict__ xs, const void* __restrict__ eidx,
        unsigned* __restrict__ tabI, unsigned* __restrict__ tabJ,
        int n, long long E, int nblkA, int NB) {
    __shared__ unsigned hi[512], hj[512];
    int lane = threadIdx.x & 63;
    if (blockIdx.x < (unsigned)nblkA) {
        // ---- hist part ----
        for (int b = threadIdx.x; b < NB; b += 256) { hi[b] = 0; hj[b] = 0; }
        __syncthreads();
        int is64 = detect64(eidx, lane);
        long long k0 = (long long)blockIdx.x * EPB;
        #pragma unroll 4
        for (int m = 0; m < EPB / 256; ++m) {
            long long k = k0 + m * 256 + threadIdx.x;
            if (k < E) {
                int j = load_idx(eidx, k, is64);       // softmax group (src)
                int i = load_idx(eidx, E + k, is64);   // destination
                atomicAdd(&hi[i >> 8], 1u);            // LDS atomics only
                atomicAdd(&hj[j >> 8], 1u);
            }
        }
        __syncthreads();
        for (int b = threadIdx.x; b < NB; b += 256) {
            tabI[(size_t)b * nblkA + blockIdx.x] = hi[b];
            tabJ[(size_t)b * nblkA + blockIdx.x] = hj[b];
        }
    } else {
        // ---- logits + int8 quant part ----
        int blk = blockIdx.x - nblkA;
        int wave = blk * 4 + (int)(threadIdx.x >> 6);
        if (wave >= n) return;
        const float2* xr = (const float2*)(x + (long long)wave * N_HID);
        float2 v  = xr[lane];
        float2 wi = ((const float2*)w_i)[lane];
        float2 wj = ((const float2*)w_j)[lane];
        float si = v.x * wi.x + v.y * wi.y;
        float sj = v.x * wj.x + v.y * wj.y;
        float am = fmaxf(fabsf(v.x), fabsf(v.y));
        #pragma unroll
        for (int off = 32; off >= 1; off >>= 1) {
            si += __shfl_xor(si, off);
            sj += __shfl_xor(sj, off);
            am = fmaxf(am, __shfl_xor(am, off));
        }
        if (xq) {
            float inv = 127.f / fmaxf(am, 1e-20f);
            int q0 = (int)rintf(v.x * inv);
            int q1 = (int)rintf(v.y * inv);
            q0 = min(127, max(-127, q0));
            q1 = min(127, max(-127, q1));
            ushort pk = (ushort)((q0 & 0xff) | ((q1 & 0xff) << 8));
            ((ushort*)(xq + (size_t)wave * N_HID))[lane] = pk;
        }
        if (lane == 0) {
            ei_all[wave] = si;
            ej_all[wave] = sj;
            if (xq) xs[wave] = fmaxf(am, 1e-20f) * (1.f / 127.f);
        }
    }
}

// ---------------------------------------------------------------------------
// 2-level exclusive scan over the CONCATENATED [tabI | tabJ] table.
// Block-offset correction (bs1) applied lazily at read time via TABV.
// tabJ entries carry +E bias (total of tabI); consumers subtract E.
// ---------------------------------------------------------------------------
__global__ __launch_bounds__(SCB) void scanT1_k(unsigned* __restrict__ a,
                                                unsigned* __restrict__ bs, int nt) {
    __shared__ unsigned tmp[SCB];
    int gid = blockIdx.x * SCB + threadIdx.x;
    unsigned v = (gid < nt) ? a[gid] : 0;
    tmp[threadIdx.x] = v;
    __syncthreads();
    for (int off = 1; off < SCB; off <<= 1) {
        unsigned t = (threadIdx.x >= off) ? tmp[threadIdx.x - off] : 0;
        __syncthreads();
        tmp[threadIdx.x] += t;
        __syncthreads();
    }
    if (gid < nt) a[gid] = tmp[threadIdx.x] - v;   // exclusive within block
    if (threadIdx.x == SCB - 1) bs[blockIdx.x] = tmp[threadIdx.x];
}

__global__ __launch_bounds__(SCB) void scanT2_k(unsigned* __restrict__ bs, int nb) {
    __shared__ unsigned tmp[SCB];
    unsigned v = (threadIdx.x < nb) ? bs[threadIdx.x] : 0;
    tmp[threadIdx.x] = v;
    __syncthreads();
    for (int off = 1; off < SCB; off <<= 1) {
        unsigned t = (threadIdx.x >= off) ? tmp[threadIdx.x - off] : 0;
        __syncthreads();
        tmp[threadIdx.x] += t;
        __syncthreads();
    }
    if (threadIdx.x < nb) bs[threadIdx.x] = tmp[threadIdx.x] - v;  // exclusive
}

// ---------------------------------------------------------------------------
// K3 (scatter2): same block<->edge mapping as hist. Places
//   srecI: (i&255)<<17 | j   at bucket-region cursor for i>>8
//   srecJ: (j&255)<<17 | i   at bucket-region cursor for j>>8
// via LDS cursors. No global atomics.
// ---------------------------------------------------------------------------
__global__ __launch_bounds__(256) void scatter2_k(
        const void* __restrict__ eidx, const unsigned* __restrict__ tab,
        const unsigned* __restrict__ bs1, unsigned* __restrict__ srecI,
        unsigned* __restrict__ srecJ, long long E, int nblkA, int NB, int NT) {
    __shared__ unsigned ci[512], cj[512];
    unsigned Eu = (unsigned)E;
    for (int b = threadIdx.x; b < NB; b += 256) {
        size_t gI = (size_t)b * nblkA + blockIdx.x;
        size_t gJ = (size_t)NT + gI;
        ci[b] = TABV(gI);
        cj[b] = TABV(gJ) - Eu;   // unbias
    }
    __syncthreads();
    int is64 = detect64(eidx, threadIdx.x & 63);
    long long k0 = (long long)blockIdx.x * EPB;
    #pragma unroll 4
    for (int m = 0; m < EPB / 256; ++m) {
        long long k = k0 + m * 256 + threadIdx.x;
        if (k < E) {
            int j = load_idx(eidx, k, is64);
            int i = load_idx(eidx, E + k, is64);
            unsigned pI = atomicAdd(&ci[i >> 8], 1u);   // LDS atomic
            srecI[pI] = ((unsigned)(i & 255) << 17) | (unsigned)j;
            unsigned pJ = atomicAdd(&cj[j >> 8], 1u);   // LDS atomic
            srecJ[pJ] = ((unsigned)(j & 255) << 17) | (unsigned)i;
        }
    }
}

// ---------------------------------------------------------------------------
// K4 (finalizeJ): one 512-thread workgroup per j-bucket. denom[j] = sum of
// exp(leaky(ei[i]+ej[j])) over the bucket's records, accumulated in LDS.
// Writes packed (ej, denom) float2 for finalizeI.
// ---------------------------------------------------------------------------
__global__ __launch_bounds__(512) void finalizeJ_k(
        const unsigned* __restrict__ srecJ, const unsigned* __restrict__ tab,
        const unsigned* __restrict__ bs1, const float* __restrict__ ei_all,
        const float* __restrict__ ej_all, float2* __restrict__ ejd,
        int n, long long E, int nblkA, int NB, int NT) {
    int b = blockIdx.x;
    int tid = threadIdx.x;
    unsigned Eu = (unsigned)E;
    size_t gJ0 = (size_t)NT + (size_t)b * nblkA;
    int base = (int)(TABV(gJ0) - Eu);
    int end  = (b + 1 < NB) ? (int)(TABV(gJ0 + nblkA) - Eu) : (int)E;

    __shared__ float ejl[256];
    __shared__ float dsum[256];
    int g = b * 256 + tid;
    if (tid < 256) {
        ejl[tid]  = (g < n) ? ej_all[g] : 0.f;
        dsum[tid] = 0.f;
    }
    __syncthreads();

    for (int t = base + tid; t < end; t += 512) {
        unsigned r = srecJ[t];
        int jl = (int)(r >> 17);
        int i  = (int)(r & 0x1FFFFu);
        float e = ei_all[i] + ejl[jl];
        e = e > 0.f ? e : LEAKY * e;
        atomicAdd(&dsum[jl], __expf(e));          // LDS float atomic
    }
    __syncthreads();
    if (tid < 256 && g < n) {
        float2 r2;
        r2.x = ejl[tid];
        r2.y = dsum[tid];
        ejd[g] = r2;
    }
}

// ---------------------------------------------------------------------------
// K5 (finalizeI): one 512-thread workgroup per i-bucket (256 nodes). LDS
// per-node counts + scan -> exact CSR start[]; alpha = exp(leaky)/denom via
// one float2 gather; LDS-ranked slot; pje[slot] = j<<15 | round(alpha*32768).
// ---------------------------------------------------------------------------
__global__ __launch_bounds__(512) void finalizeI_k(
        const unsigned* __restrict__ srecI, const unsigned* __restrict__ tab,
        const unsigned* __restrict__ bs1, const float* __restrict__ ei_all,
        const float2* __restrict__ ejd, int* __restrict__ start,
        unsigned* __restrict__ pje, int n, long long E, int nblkA, int NB,
        int NT) {
    int b = blockIdx.x;
    int tid = threadIdx.x;
    size_t gI0 = (size_t)b * nblkA;
    int base = (int)TABV(gI0);
    int end  = (b + 1 < NB) ? (int)TABV(gI0 + nblkA) : (int)E;

    __shared__ int cnt[256];
    __shared__ int off[256];
    __shared__ float eil[256];
    int g = b * 256 + tid;
    if (tid < 256) {
        cnt[tid] = 0;
        eil[tid] = (g < n) ? ei_all[g] : 0.f;
    }
    __syncthreads();

    for (int t = base + tid; t < end; t += 512)
        atomicAdd(&cnt[srecI[t] >> 17], 1);
    __syncthreads();

    // exclusive scan of cnt[256] (threads >=256 only hit the barriers)
    int v = 0;
    if (tid < 256) { v = cnt[tid]; off[tid] = v; }
    __syncthreads();
    for (int s = 1; s < 256; s <<= 1) {
        int t2 = 0;
        if (tid < 256 && tid >= s) t2 = off[tid - s];
        __syncthreads();
        if (tid < 256) off[tid] += t2;
        __syncthreads();
    }
    if (tid < 256) {
        int excl = off[tid] - v;
        if (g < n) start[g] = base + excl;
        cnt[tid] = excl;   // reuse as cursor
    }
    if (b == NB - 1 && tid == 0) start[n] = (int)E;
    __syncthreads();

    for (int t = base + tid; t < end; t += 512) {
        unsigned r = srecI[t];
        int il = (int)(r >> 17);
        int j  = (int)(r & 0x1FFFFu);
        float2 ed = ejd[j];                       // (ej, denom) in one load
        float e = eil[il] + ed.x;
        e = e > 0.f ? e : LEAKY * e;
        float alpha = __expf(e) / ed.y;
        unsigned aq = __float2uint_rn(alpha * 32768.f);
        if (aq > 32767u) aq = 32767u;
        int slot = base + atomicAdd(&cnt[il], 1);
        pje[slot] = ((unsigned)j << 15) | aq;
    }
}

// ---------------------------------------------------------------------------
// K6a: int8 gather: wave/node, 8 lanes per row (uint4 = 16 int8 each), so
// one load instruction covers 8 edges; 2 independent loads/iter = 16 edges.
// Row = 128 B (2 sectors) -- half the bf16 traffic. alpha premultiplied by
// the per-row scale xs[j]. Tail slots decode to alpha=0, row 0 (L1-hot).
// Fold 8 sub-groups with shfl_xor(8|16|32); fused relu; float4 stores.
// ---------------------------------------------------------------------------
#define ACC4(w, A, B, C, D, af)                      \
    A += af * (float)((int)((w) << 24) >> 24);       \
    B += af * (float)((int)((w) << 16) >> 24);       \
    C += af * (float)((int)((w) <<  8) >> 24);       \
    D += af * (float)((int)(w) >> 24);

__global__ __launch_bounds__(256) void gather_i8_k(
        const int* __restrict__ start, const unsigned* __restrict__ pje,
        const signed char* __restrict__ xq, const float* __restrict__ xs,
        float* __restrict__ out, int n) {
    int wave = (int)((blockIdx.x * (long long)blockDim.x + threadIdx.x) >> 6);
    int lane = threadIdx.x & 63;
    if (wave >= n) return;
    int s = start[wave];
    int e_end = start[wave + 1];
    int sub = lane >> 3;        // which edge of the octet (0..7)
    int col = lane & 7;         // 16B chunk within row (elems 16col..16col+15)

    float t0 = 0.f, t1 = 0.f, t2 = 0.f, t3 = 0.f;
    float t4 = 0.f, t5 = 0.f, t6 = 0.f, t7 = 0.f;
    float t8 = 0.f, t9 = 0.f, tA = 0.f, tB = 0.f;
    float tC = 0.f, tD = 0.f, tE = 0.f, tF = 0.f;
    for (int e = s; e < e_end; e += 16) {
        int ee0 = e + sub;
        int ee1 = e + 8 + sub;
        unsigned c0 = (ee0 < e_end) ? pje[ee0] : 0u;   // 0 -> alpha=0, row 0
        unsigned c1 = (ee1 < e_end) ? pje[ee1] : 0u;
        int j0 = (int)(c0 >> 15), j1 = (int)(c1 >> 15);
        float a0 = (float)(c0 & 0x7FFFu) * (1.f / 32768.f) * xs[j0];
        float a1 = (float)(c1 & 0x7FFFu) * (1.f / 32768.f) * xs[j1];
        uint4 u0 = ((const uint4*)(xq + (size_t)j0 * N_HID))[col];
        uint4 u1 = ((const uint4*)(xq + (size_t)j1 * N_HID))[col];
        ACC4(u0.x, t0, t1, t2, t3, a0)
        ACC4(u0.y, t4, t5, t6, t7, a0)
        ACC4(u0.z, t8, t9, tA, tB, a0)
        ACC4(u0.w, tC, tD, tE, tF, a0)
        ACC4(u1.x, t0, t1, t2, t3, a1)
        ACC4(u1.y, t4, t5, t6, t7, a1)
        ACC4(u1.z, t8, t9, tA, tB, a1)
        ACC4(u1.w, tC, tD, tE, tF, a1)
    }
    // fold the 8 sub-groups (lanes differing in bits 3,4,5)
    #pragma unroll
    for (int off = 8; off <= 32; off <<= 1) {
        t0 += __shfl_xor(t0, off); t1 += __shfl_xor(t1, off);
        t2 += __shfl_xor(t2, off); t3 += __shfl_xor(t3, off);
        t4 += __shfl_xor(t4, off); t5 += __shfl_xor(t5, off);
        t6 += __shfl_xor(t6, off); t7 += __shfl_xor(t7, off);
        t8 += __shfl_xor(t8, off); t9 += __shfl_xor(t9, off);
        tA += __shfl_xor(tA, off); tB += __shfl_xor(tB, off);
        tC += __shfl_xor(tC, off); tD += __shfl_xor(tD, off);
        tE += __shfl_xor(tE, off); tF += __shfl_xor(tF, off);
    }
    if (sub == 0) {
        float4* orow = (float4*)(out + (size_t)wave * N_HID);
        float4 r;
        r.x = fmaxf(t0, 0.f); r.y = fmaxf(t1, 0.f);
        r.z = fmaxf(t2, 0.f); r.w = fmaxf(t3, 0.f);
        orow[col * 4 + 0] = r;
        r.x = fmaxf(t4, 0.f); r.y = fmaxf(t5, 0.f);
        r.z = fmaxf(t6, 0.f); r.w = fmaxf(t7, 0.f);
        orow[col * 4 + 1] = r;
        r.x = fmaxf(t8, 0.f); r.y = fmaxf(t9, 0.f);
        r.z = fmaxf(tA, 0.f); r.w = fmaxf(tB, 0.f);
        orow[col * 4 + 2] = r;
        r.x = fmaxf(tC, 0.f); r.y = fmaxf(tD, 0.f);
        r.z = fmaxf(tE, 0.f); r.w = fmaxf(tF, 0.f);
        orow[col * 4 + 3] = r;
    }
}

// K6b: fallback gather reading f32 x directly (if ws too small for xq/xs).
__global__ __launch_bounds__(256) void gather_f32_k(
        const int* __restrict__ start, const unsigned* __restrict__ pje,
        const float* __restrict__ x, float* __restrict__ out, int n) {
    int wave = (int)((blockIdx.x * (long long)blockDim.x + threadIdx.x) >> 6);
    int lane = threadIdx.x & 63;
    if (wave >= n) return;
    int s = start[wave];
    int e_end = start[wave + 1];
    float ax = 0.f, ay = 0.f;
    unsigned ja = 0;
    if (s < e_end) ja = pje[s];
    for (int e = s; e < e_end; ++e) {
        unsigned cur = ja;
        if (e + 1 < e_end) ja = pje[e + 1];
        float a = (float)(cur & 0x7FFFu) * (1.f / 32768.f);
        float2 v = ((const float2*)(x + (long long)(cur >> 15) * N_HID))[lane];
        ax += a * v.x;
        ay += a * v.y;
    }
    float2 r;
    r.x = fmaxf(ax, 0.f);
    r.y = fmaxf(ay, 0.f);
    ((float2*)(out + (long long)wave * N_HID))[lane] = r;
}

extern "C" void kernel_launch(void* const* d_in, const int* in_sizes, int n_in,
                              void* d_out, int out_size, void* d_ws,
                              size_t ws_size, hipStream_t stream) {
    const float* x   = (const float*)d_in[0];
    const void*  eix = d_in[1];
    const float* w_i = (const float*)d_in[2];
    const float* w_j = (const float*)d_in[3];
    float* out = (float*)d_out;

    int n = in_sizes[0] / N_HID;            // 100000
    long long E = in_sizes[1] / 2;          // 1.6M

    int nblkA = (int)((E + EPB - 1) / EPB); // 782
    int nblkL = (n + 3) / 4;                // logits blocks (4 nodes/block)
    int NB    = (n + 255) / 256;            // 391 (<= 512 required)
    int NT    = NB * nblkA;                 // ~306k
    int NT2   = 2 * NT;                     // combined tabI|tabJ scan ~611k
    int nb1   = (NT2 + SCB - 1) / SCB;      // ~598 (<= 1024 required)

    // ws layout (bytes), ~30.7 MB total:
    //   ei[n] ej[n] f32 | ejd[n] float2 | start[n+1] int | tab[2*NT] u32
    //   bs1[SCB] u32 | srecI[E] u32 | pje[E] u32 (aliases srecJ)
    //   xq[n*128] i8 | xs[n] f32 (optional)
    // srecJ aliases pje: srecJ is fully consumed by finalizeJ BEFORE
    // finalizeI writes pje.
    char* p = (char*)d_ws;
    float* ei_all = (float*)p;               p += (size_t)n * 4;
    float* ej_all = (float*)p;               p += (size_t)n * 4;
    float2* ejd   = (float2*)p;              p += (size_t)n * 8;
    int*   start  = (int*)p;                 p += ((size_t)(n + 1) * 4 + 15) & ~15ull;
    unsigned* tab = (unsigned*)p;            p += ((size_t)NT2 * 4 + 15) & ~15ull;
    unsigned* tabI = tab;
    unsigned* tabJ = tab + NT;               // contiguous for combined scan
    unsigned* bs1 = (unsigned*)p;            p += (size_t)SCB * 4;
    unsigned* srecI = (unsigned*)p;          p += (size_t)E * 4;
    unsigned* pje   = (unsigned*)p;          p += (size_t)E * 4;
    unsigned* srecJ = pje;                   // alias (see above)
    signed char* xq = (signed char*)p;       p += ((size_t)n * N_HID + 15) & ~15ull;
    float* xs     = (float*)p;               p += (size_t)n * 4;
    int wsBig = ((size_t)(p - (char*)d_ws) <= ws_size);
    if (!wsBig) { xq = nullptr; xs = nullptr; }

    logits_hist_k<<<(unsigned)(nblkA + nblkL), 256, 0, stream>>>(
        x, w_i, w_j, ei_all, ej_all, xq, xs, eix, tabI, tabJ, n, E, nblkA, NB);

    scanT1_k<<<nb1, SCB, 0, stream>>>(tab, bs1, NT2);
    scanT2_k<<<1, SCB, 0, stream>>>(bs1, nb1);

    scatter2_k<<<nblkA, 256, 0, stream>>>(eix, tab, bs1, srecI, srecJ,
                                          E, nblkA, NB, NT);

    finalizeJ_k<<<NB, 512, 0, stream>>>(srecJ, tab, bs1, ei_all, ej_all, ejd,
                                        n, E, nblkA, NB, NT);

    finalizeI_k<<<NB, 512, 0, stream>>>(srecI, tab, bs1, ei_all, ejd,
                                        start, pje, n, E, nblkA, NB, NT);

    long long t4 = (long long)n * 64;
    if (wsBig) {
        gather_i8_k<<<(unsigned)((t4 + 255) / 256), 256, 0, stream>>>(
            start, pje, xq, xs, out, n);
    } else {
        gather_f32_k<<<(unsigned)((t4 + 255) / 256), 256, 0, stream>>>(
            start, pje, x, out, n);
    }
}